// Round 11
// baseline (176.229 us; speedup 1.0000x reference)
//
#include <hip/hip_runtime.h>
#include <cstdint>
#include <cmath>
#include <cstddef>

#pragma clang fp contract(off)

#define QMAXF 127.0f

typedef int i32x4 __attribute__((ext_vector_type(4)));

enum {
  S_X = 0, S_WQ, S_WK, S_WV, S_WO, S_BQ, S_BK, S_BV, S_BO,
  S_YQ, S_YK, S_YV, S_CTX, S_CTXQ1, S_DMIN, S_PAD
};

struct PLA { float m[12]; float c[12]; float a[12]; };

#define GLOAD_LDS16(gsrc, ldst) \
  __builtin_amdgcn_global_load_lds((const __attribute__((address_space(1))) void*)(gsrc), \
                                   (__attribute__((address_space(3))) void*)(ldst), 16, 0, 0)

// ---------------- device helpers ----------------

__device__ __forceinline__ float qscale(const unsigned* scal, int slot) {
  // reference: scale = max(maxabs / 127.0, 1e-8)
  return fmaxf(__uint_as_float(scal[slot]) / QMAXF, 1e-8f);
}

// Markstein correctly-rounded division with hoisted refined reciprocal (validated R6/R8).
__device__ __forceinline__ float refined_rcp(float d) {
  float rd = __builtin_amdgcn_rcpf(d);
  return fmaf(fmaf(-d, rd, 1.0f), rd, rd);
}
__device__ __forceinline__ float fdiv_m(float v, float d, float rd) {
  float q0 = v * rd;
  float r = fmaf(-d, q0, v);
  return fmaf(r, rd, q0);
}

// v_med3_f32 clamp (equivalent to fminf(fmaxf(x,lo),hi) for non-NaN x; our inputs never NaN)
__device__ __forceinline__ float clamp3(float x, float lo, float hi) {
  return __builtin_amdgcn_fmed3f(x, lo, hi);
}

__device__ __forceinline__ void block_atomic_maxf(float v, unsigned* slot) {
  for (int off = 32; off > 0; off >>= 1) v = fmaxf(v, __shfl_xor(v, off, 64));
  __shared__ float red4[4];
  int lane = threadIdx.x & 63, w = threadIdx.x >> 6;
  if (lane == 0) red4[w] = v;
  __syncthreads();
  if (threadIdx.x == 0)
    atomicMax(slot, __float_as_uint(fmaxf(fmaxf(red4[0], red4[1]), fmaxf(red4[2], red4[3]))));
}

__device__ __forceinline__ int qpack4(float a0, float a1, float a2, float a3, float s) {
  int i0 = (int)clamp3(rintf(a0 / s), -QMAXF, QMAXF);
  int i1 = (int)clamp3(rintf(a1 / s), -QMAXF, QMAXF);
  int i2 = (int)clamp3(rintf(a2 / s), -QMAXF, QMAXF);
  int i3 = (int)clamp3(rintf(a3 / s), -QMAXF, QMAXF);
  return (i0 & 255) | ((i1 & 255) << 8) | ((i2 & 255) << 16) | ((i3 & 255) << 24);
}

__device__ __forceinline__ float fabs4max(float4 v) {
  return fmaxf(fmaxf(fabsf(v.x), fabsf(v.y)), fmaxf(fabsf(v.z), fabsf(v.w)));
}

// ---------------- fused maxabs: X + 4 weights + 4 biases ----------------

__global__ __launch_bounds__(256) void maxabs_all(const float4* __restrict__ X,
                                                  const float4* __restrict__ w0, const float4* __restrict__ w1,
                                                  const float4* __restrict__ w2, const float4* __restrict__ w3,
                                                  const float* __restrict__ b0, const float* __restrict__ b1,
                                                  const float* __restrict__ b2, const float* __restrict__ b3,
                                                  unsigned* __restrict__ scal) {
  int blk = blockIdx.x, t = threadIdx.x;
  float m = 0.0f;
  unsigned* slot;
  if (blk < 1024) {
    int i = blk * 256 + t;
#pragma unroll
    for (int k = 0; k < 3; ++k) m = fmaxf(m, fabs4max(X[i + k * 262144]));
    slot = scal + S_X;
  } else if (blk < 1600) {
    int which = (blk - 1024) / 144, j = (blk - 1024) % 144;
    const float4* p = which == 0 ? w0 : which == 1 ? w1 : which == 2 ? w2 : w3;
    int i = j * 256 + t;
#pragma unroll
    for (int k = 0; k < 4; ++k) m = fmaxf(m, fabs4max(p[i + k * 36864]));
    slot = scal + S_WQ + which;
  } else {
    int which = blk - 1600;
    const float* p = which == 0 ? b0 : which == 1 ? b1 : which == 2 ? b2 : b3;
    for (int i = t; i < 768; i += 256) m = fmaxf(m, fabsf(p[i]));
    slot = scal + S_BQ + which;
  }
  block_atomic_maxf(m, slot);
}

// ---------------- fused quant: X + 4 weights + qbias(q,k,v) ----------------

__device__ __forceinline__ void qbias_body(const float* __restrict__ b, float* __restrict__ qb,
                                           const unsigned* __restrict__ scal, int slotX, int slotW, int slotB, int j) {
  if (j >= 768) return;
  float in_scale = __uint_as_float(scal[slotX]) / QMAXF;   // no clamp (reference)
  float w_scale  = __uint_as_float(scal[slotW]) / QMAXF;
  float bias_scale = in_scale * w_scale;
  float tmax = __uint_as_float(scal[slotB]) / bias_scale;
  float st = fmaxf(tmax / QMAXF, 1e-8f);
  float t = b[j] / bias_scale;
  float qv = fminf(fmaxf(rintf(t / st), -127.0f), 127.0f) * st;
  qb[j] = qv * bias_scale;
}

__global__ __launch_bounds__(256) void quant_all(const float4* __restrict__ X, int* __restrict__ qX,
                                                 const float4* __restrict__ w0, const float4* __restrict__ w1,
                                                 const float4* __restrict__ w2, const float4* __restrict__ w3,
                                                 int* __restrict__ o0, int* __restrict__ o1,
                                                 int* __restrict__ o2, int* __restrict__ o3,
                                                 const float* __restrict__ bq, const float* __restrict__ bk,
                                                 const float* __restrict__ bv,
                                                 float* __restrict__ qbq, float* __restrict__ qbk,
                                                 float* __restrict__ qbv,
                                                 const unsigned* __restrict__ scal) {
  int blk = blockIdx.x, t = threadIdx.x;
  if (blk < 1024) {
    float s = qscale(scal, S_X);
    int i = blk * 256 + t;
#pragma unroll
    for (int k = 0; k < 3; ++k) {
      float4 v = X[i + k * 262144];
      qX[i + k * 262144] = qpack4(v.x, v.y, v.z, v.w, s);
    }
  } else if (blk < 1600) {
    int which = (blk - 1024) / 144, j = (blk - 1024) % 144;
    const float4* p = which == 0 ? w0 : which == 1 ? w1 : which == 2 ? w2 : w3;
    int* o = which == 0 ? o0 : which == 1 ? o1 : which == 2 ? o2 : o3;
    float s = qscale(scal, S_WQ + which);
    int i = j * 256 + t;
#pragma unroll
    for (int k = 0; k < 4; ++k) {
      float4 v = p[i + k * 36864];
      o[i + k * 36864] = qpack4(v.x, v.y, v.z, v.w, s);
    }
  } else {
    int proj = (blk - 1600) / 3, part = (blk - 1600) % 3;
    int j = part * 256 + t;
    const float* b = proj == 0 ? bq : proj == 1 ? bk : bv;
    float* qb = proj == 0 ? qbq : proj == 1 ? qbk : qbv;
    qbias_body(b, qb, scal, S_X, S_WQ + proj, S_BQ + proj, j);
  }
}

// ---------------- LDS-staged MFMA int8 GEMM (proven R5/R6 structure) ----------------

__device__ __forceinline__ void gemm_body(const int8_t* __restrict__ A, const int8_t* __restrict__ Bm,
                                          float* __restrict__ C, const float* __restrict__ bias,
                                          unsigned* __restrict__ scal, int slotA, int slotB, int maxslot) {
  __shared__ int8_t Al[16384];
  __shared__ int8_t Bl[8192];
  int t = threadIdx.x, lane = t & 63, w = t >> 6, l15 = lane & 15, kg4 = lane >> 4;
  int bm = blockIdx.y * 128, bn = blockIdx.x * 64;
  float sAB = qscale(scal, slotA) * qscale(scal, slotB);
  int srow = t >> 3, scol = (t & 7) * 16;
  int ssw = scol ^ ((srow & 7) << 4);
  i32x4 acc[2][4];
#pragma unroll
  for (int rt = 0; rt < 2; ++rt)
#pragma unroll
    for (int ct = 0; ct < 4; ++ct)
#pragma unroll
      for (int r = 0; r < 4; ++r) acc[rt][ct][r] = 0;

  for (int kt = 0; kt < 6; ++kt) {
    int kc = kt * 128;
#pragma unroll
    for (int j = 0; j < 4; ++j) {
      int r = j * 32 + srow;
      GLOAD_LDS16(A + (size_t)(bm + r) * 768 + kc + ssw, Al + r * 128 + scol);
    }
#pragma unroll
    for (int j = 0; j < 2; ++j) {
      int r = j * 32 + srow;
      GLOAD_LDS16(Bm + (size_t)(bn + r) * 768 + kc + ssw, Bl + r * 128 + scol);
    }
    __syncthreads();
#pragma unroll
    for (int kg = 0; kg < 2; ++kg) {
      int kcol = kg * 64 + kg4 * 16;
      i32x4 af[2], bf[4];
#pragma unroll
      for (int rt = 0; rt < 2; ++rt) {
        int ar = w * 32 + rt * 16 + l15;
        af[rt] = *(const i32x4*)(Al + ar * 128 + (kcol ^ ((ar & 7) << 4)));
      }
#pragma unroll
      for (int ct = 0; ct < 4; ++ct) {
        int br = ct * 16 + l15;
        bf[ct] = *(const i32x4*)(Bl + br * 128 + (kcol ^ ((br & 7) << 4)));
      }
#pragma unroll
      for (int rt = 0; rt < 2; ++rt)
#pragma unroll
        for (int ct = 0; ct < 4; ++ct)
          acc[rt][ct] = __builtin_amdgcn_mfma_i32_16x16x64_i8(af[rt], bf[ct], acc[rt][ct], 0, 0, 0);
    }
    __syncthreads();
  }
  float am = 0.0f;
#pragma unroll
  for (int rt = 0; rt < 2; ++rt)
#pragma unroll
    for (int ct = 0; ct < 4; ++ct) {
      int col = bn + ct * 16 + l15;
      float bv = bias[col];
#pragma unroll
      for (int r = 0; r < 4; ++r) {
        int row = bm + w * 32 + rt * 16 + kg4 * 4 + r;
        float v = (float)acc[rt][ct][r] * sAB;
        float yv = v + bv;
        C[(size_t)row * 768 + col] = yv;
        am = fmaxf(am, fabsf(yv));
      }
    }
  if (maxslot >= 0) block_atomic_maxf(am, scal + maxslot);
}

__global__ __launch_bounds__(256) void gemm_qkv(const int8_t* __restrict__ qX,
                                                const int8_t* __restrict__ qWq, const int8_t* __restrict__ qWk,
                                                const int8_t* __restrict__ qWv,
                                                const float* __restrict__ qbq, const float* __restrict__ qbk,
                                                const float* __restrict__ qbv,
                                                float* __restrict__ Yq, float* __restrict__ Yk, float* __restrict__ Yv,
                                                unsigned* __restrict__ scal) {
  int z = blockIdx.z;
  const int8_t* Bm = z == 0 ? qWq : z == 1 ? qWk : qWv;
  const float* bias = z == 0 ? qbq : z == 1 ? qbk : qbv;
  float* C = z == 0 ? Yq : z == 1 ? Yk : Yv;
  gemm_body(qX, Bm, C, bias, scal, S_X, S_WQ + z, S_YQ + z);
}

__global__ __launch_bounds__(256) void gemm_proj(const int8_t* __restrict__ A, const int8_t* __restrict__ Bm,
                                                 float* __restrict__ C, const float* __restrict__ bias,
                                                 unsigned* __restrict__ scal, int slotA, int slotB, int maxslot) {
  gemm_body(A, Bm, C, bias, scal, slotA, slotB, maxslot);
}

// ---------------- head re-layout + quant ----------------

__device__ __forceinline__ void qheads_qk_body(const float* __restrict__ Y, int* __restrict__ q,
                                               const unsigned* __restrict__ scal, int slot, int i) {
  float s = qscale(scal, slot);
  int d0 = (i & 15) * 4;
  int sI = (i >> 4) & 511;
  int bh = i >> 13;
  int h = bh % 12, b = bh / 12;
  const float* src = Y + ((size_t)(b * 512 + sI)) * 768 + h * 64 + d0;
  float4 v = *(const float4*)src;
  q[i] = qpack4(v.x, v.y, v.z, v.w, s);
}

__device__ __forceinline__ void qheads_v_body(const float* __restrict__ Y, int8_t* __restrict__ q,
                                              const unsigned* __restrict__ scal, int blkv) {
  __shared__ int8_t T[64][68];
  int bh = blkv >> 3, sb = blkv & 7;
  int b = bh / 12, h = bh % 12;
  float s = qscale(scal, S_YV);
  int d = threadIdx.x & 63, sl = threadIdx.x >> 6;
#pragma unroll
  for (int i = 0; i < 16; ++i) {
    int s_local = i * 4 + sl;
    float y = Y[((size_t)(b * 512 + sb * 64 + s_local)) * 768 + h * 64 + d];
    float tq = clamp3(rintf(y / s), -QMAXF, QMAXF);
    T[d][s_local] = (int8_t)tq;
  }
  __syncthreads();
  int s4 = (threadIdx.x & 15) * 4, dl = threadIdx.x >> 4;
#pragma unroll
  for (int i = 0; i < 4; ++i) {
    int d_ = i * 16 + dl;
    int packed = (T[d_][s4] & 255) | ((T[d_][s4 + 1] & 255) << 8) |
                 ((T[d_][s4 + 2] & 255) << 16) | ((T[d_][s4 + 3] & 255) << 24);
    *(int*)(q + (size_t)bh * 32768 + (size_t)d_ * 512 + sb * 64 + s4) = packed;
  }
}

__global__ __launch_bounds__(256) void quant_heads_all(const float* __restrict__ Yq, int* __restrict__ qq,
                                                       const float* __restrict__ Yk, int* __restrict__ qk,
                                                       const float* __restrict__ Yv, int8_t* __restrict__ qvT,
                                                       const unsigned* __restrict__ scal) {
  int blk = blockIdx.x;
  if (blk < 3072)      qheads_qk_body(Yq, qq, scal, S_YQ, blk * 256 + threadIdx.x);
  else if (blk < 6144) qheads_qk_body(Yk, qk, scal, S_YK, (blk - 3072) * 256 + threadIdx.x);
  else                 qheads_v_body(Yv, qvT, scal, blk - 6144);
}

__global__ __launch_bounds__(256) void quant_heads_qk(const float* __restrict__ Y, int* __restrict__ q,
                                                      const unsigned* __restrict__ scal, int slot) {
  qheads_qk_body(Y, q, scal, slot, blockIdx.x * 256 + threadIdx.x);
}
__global__ __launch_bounds__(256) void quant_heads_v(const float* __restrict__ Y, int8_t* __restrict__ q,
                                                     const unsigned* __restrict__ scal) {
  qheads_v_body(Y, q, scal, blockIdx.x);
}

// ---------------- attention e-phase (4-wave, float4-table + fma-estimate version) ----------------
// tab[i] = (a[i], a[i+1], m[i], c[i]) for i<=9; tab[10] = (a[10], +BIG, m[10], c[10]);
// tab[11..12] = (-BIG, +BIG, m[10], c[10]) -- encodes the reference's clip(idx,10) quirk.
// i0 estimate: tf = fma(sh, 1.2*2^-26, 12.0) (exact at xc=0 -> 12); estimate error ~1e-5
// of an interval, so the +-1 correction (rare, exec-masked re-read) yields the EXACT
// searchsorted index. e-values bit-identical to R5-R10.

__device__ __forceinline__ void attn_e_phase(const int8_t* __restrict__ qbase,
                                             const int8_t* __restrict__ kbase,
                                             int rb, float pref, const PLA& pla,
                                             float (&v)[8][4], float (*red)[16], float& denom) {
  __shared__ float4 tab[13];
  int t = threadIdx.x, lane = t & 63, w = t >> 6, l15 = lane & 15, kg = lane >> 4;
  if (t < 13) {
    if (t < 10)       tab[t] = make_float4(pla.a[t], pla.a[t + 1], pla.m[t], pla.c[t]);
    else if (t == 10) tab[t] = make_float4(pla.a[10], 3.4e38f, pla.m[10], pla.c[10]);
    else              tab[t] = make_float4(-3.4e38f, 3.4e38f, pla.m[10], pla.c[10]);
  }
  i32x4 zero = {0, 0, 0, 0};
  i32x4 qf = *(const i32x4*)(qbase + (size_t)(rb * 16 + l15) * 64 + kg * 16);
  i32x4 acc[8];
#pragma unroll
  for (int i = 0; i < 8; ++i) {
    i32x4 kf = *(const i32x4*)(kbase + (size_t)((w * 8 + i) * 16 + l15) * 64 + kg * 16);
    acc[i] = __builtin_amdgcn_mfma_i32_16x16x64_i8(kf, qf, zero, 0, 0, 0);
  }
  float mx = -3.4e38f;
#pragma unroll
  for (int i = 0; i < 8; ++i)
#pragma unroll
    for (int r = 0; r < 4; ++r) {
      v[i][r] = (float)acc[i][r] * pref;
      mx = fmaxf(mx, v[i][r]);
    }
  mx = fmaxf(mx, __shfl_xor(mx, 16, 64));
  mx = fmaxf(mx, __shfl_xor(mx, 32, 64));
  if (lane < 16) red[w][l15] = mx;
  __syncthreads();                     // also covers tab init
  float gm = fmaxf(fmaxf(red[0][l15], red[1][l15]), fmaxf(red[2][l15], red[3][l15]));
  __syncthreads();
  const float K1 = 1.2f * (1.0f / 67108864.0f);
  float s = 0.0f;
#pragma unroll
  for (int i = 0; i < 8; ++i)
#pragma unroll
    for (int r = 0; r < 4; ++r) {
      float x = v[i][r] - gm;
      float sh = clamp3(rintf(x * 67108864.0f), -671088640.0f, 0.0f);
      float xc = sh * (1.0f / 67108864.0f);
      int i0 = (int)fmaf(sh, K1, 12.0f);
      float4 te = tab[i0];
      int d = ((xc >= te.y) ? 1 : 0) - ((xc < te.x) ? 1 : 0);
      float mcx = te.z, mcy = te.w;
      if (__builtin_expect(d != 0, 0)) {       // rare: xc within ~1e-5 of an edge
        float4 t2 = tab[i0 + d];
        mcx = t2.z; mcy = t2.w;
      }
      float e = mcx * xc;   // no fma: contract off
      e = e + mcy;
      v[i][r] = e;
      s += e;
    }
  s += __shfl_xor(s, 16, 64);
  s += __shfl_xor(s, 32, 64);
  if (lane < 16) red[w][l15] = s;
  __syncthreads();
  denom = (((red[0][l15] + red[1][l15]) + red[2][l15]) + red[3][l15]) + 1e-9f;
  __syncthreads();   // protect red reuse by subsequent calls
}

// ---------------- pass1: R6 4-wave structure + THREAD-MAJOR dwordx4 q15 stores ----------------

__global__ __launch_bounds__(256) void attn_pass1(const int8_t* __restrict__ qq,
                                                  const int8_t* __restrict__ qk,
                                                  int* __restrict__ q15w,
                                                  unsigned* __restrict__ scal, PLA pla) {
  __shared__ float red[4][16];
  int rb = blockIdx.x & 31, bh = blockIdx.x >> 5;
  float pref = (qscale(scal, S_YQ) * qscale(scal, S_YK)) * 0.125f;
  float v[8][4];
  float denom;
  attn_e_phase(qq + (size_t)bh * 32768, qk + (size_t)bh * 32768, rb, pref, pla, v, red, denom);
  int t = threadIdx.x;
  if (q15w) {
    float rdn = refined_rcp(denom);
    int d[16];
#pragma unroll
    for (int i = 0; i < 8; ++i) {
      int q15i[4];
#pragma unroll
      for (int r = 0; r < 4; ++r) {
        float sm32 = fdiv_m(v[i][r] * 32768.0f, denom, rdn);
        q15i[r] = (int)clamp3(rintf(sm32), -32768.0f, 32767.0f);
      }
      d[i * 2]     = (q15i[0] & 0xffff) | (q15i[1] << 16);
      d[i * 2 + 1] = (q15i[2] & 0xffff) | (q15i[3] << 16);
    }
    i32x4* q15v = (i32x4*)(q15w + (size_t)blockIdx.x * 4096);
#pragma unroll
    for (int j = 0; j < 4; ++j) {
      i32x4 pk = { d[4 * j], d[4 * j + 1], d[4 * j + 2], d[4 * j + 3] };
      q15v[j * 256 + t] = pk;
    }
  }
  if (t < 64) {
    float dm = denom;
    dm = fminf(dm, __shfl_xor(dm, 1, 64));
    dm = fminf(dm, __shfl_xor(dm, 2, 64));
    dm = fminf(dm, __shfl_xor(dm, 4, 64));
    dm = fminf(dm, __shfl_xor(dm, 8, 64));
    if (t == 0) atomicMax(scal + S_DMIN, 0x7f800000u - __float_as_uint(dm));
  }
}

__device__ __forceinline__ float derive_sp(const unsigned* scal, const PLA& pla) {
  float dmin = __uint_as_float(0x7f800000u - scal[S_DMIN]);
  float smm = pla.c[10] / dmin;
  float q15m = fminf(fmaxf(rintf(smm * 32768.0f), -32768.0f), 32767.0f);
  return fmaxf((q15m * (1.0f / 32768.0f)) / QMAXF, 1e-8f);
}

__device__ __forceinline__ void attn_pv_tail(const int8_t* __restrict__ vT, int8_t (*Ps)[528],
                                             unsigned* __restrict__ scal, float* __restrict__ ctx,
                                             int rb, int bh, float sp) {
  int t = threadIdx.x, lane = t & 63, w = t >> 6, l15 = lane & 15, kg = lane >> 4;
  int b = bh / 12, h = bh % 12;
  float sv = qscale(scal, S_YV);
  i32x4 pacc = {0, 0, 0, 0};
  const int8_t* vbase = vT + (size_t)bh * 32768 + (size_t)(w * 16 + l15) * 512;
#pragma unroll
  for (int ks = 0; ks < 8; ++ks) {
    i32x4 pf = *(const i32x4*)&Ps[l15][ks * 64 + kg * 16];
    i32x4 vf = *(const i32x4*)(vbase + ks * 64 + kg * 16);
    pacc = __builtin_amdgcn_mfma_i32_16x16x64_i8(pf, vf, pacc, 0, 0, 0);
  }
  float spv = sp * sv;
  float am = 0.0f;
#pragma unroll
  for (int r = 0; r < 4; ++r) {
    int srow = rb * 16 + kg * 4 + r;
    float val = (float)pacc[r] * spv;
    ctx[((size_t)(b * 512 + srow)) * 768 + h * 64 + w * 16 + l15] = val;
    am = fmaxf(am, fabsf(val));
  }
  block_atomic_maxf(am, scal + S_CTX);
}

__global__ __launch_bounds__(256) void attn_pass2_load(const int* __restrict__ q15r,
                                                       const int8_t* __restrict__ vT,
                                                       unsigned* __restrict__ scal,
                                                       float* __restrict__ ctx, PLA pla) {
  __shared__ alignas(16) int8_t Ps[16][528];
  int rb = blockIdx.x & 31, bh = blockIdx.x >> 5;
  float sp = derive_sp(scal, pla);
  float rsp = refined_rcp(sp);
  int t = threadIdx.x, lane = t & 63, w = t >> 6, l15 = lane & 15, kg = lane >> 4;
  const i32x4* q15v = (const i32x4*)(q15r + (size_t)blockIdx.x * 4096);
  int d[16];
#pragma unroll
  for (int j = 0; j < 4; ++j) {
    i32x4 pk = q15v[j * 256 + t];
    d[4 * j] = pk[0]; d[4 * j + 1] = pk[1]; d[4 * j + 2] = pk[2]; d[4 * j + 3] = pk[3];
  }
#pragma unroll
  for (int i = 0; i < 8; ++i) {
    int u01 = d[i * 2], u23 = d[i * 2 + 1];
    int q15i[4] = { (int)(short)(u01 & 0xffff), u01 >> 16,
                    (int)(short)(u23 & 0xffff), u23 >> 16 };
    uint32_t packed = 0;
#pragma unroll
    for (int r = 0; r < 4; ++r) {
      float pv = (float)q15i[r] * (1.0f / 32768.0f);
      int qp = (int)clamp3(rintf(fdiv_m(pv, sp, rsp)), -QMAXF, QMAXF);
      packed |= (uint32_t)(qp & 255) << (8 * r);
    }
    *(uint32_t*)&Ps[l15][(w * 8 + i) * 16 + kg * 4] = packed;
  }
  __syncthreads();
  attn_pv_tail(vT, Ps, scal, ctx, rb, bh, sp);
}

// fallback pass2: recompute e-phase (same shared helper => bit-identical), quantize, PV
__global__ __launch_bounds__(256) void attn_pass2_recompute(const int8_t* __restrict__ qq,
                                                            const int8_t* __restrict__ qk,
                                                            const int8_t* __restrict__ vT,
                                                            unsigned* __restrict__ scal,
                                                            float* __restrict__ ctx, PLA pla) {
  __shared__ float red[4][16];
  __shared__ alignas(16) int8_t Ps[16][528];
  int rb = blockIdx.x & 31, bh = blockIdx.x >> 5;
  float pref = (qscale(scal, S_YQ) * qscale(scal, S_YK)) * 0.125f;
  float sp = derive_sp(scal, pla);
  float rsp = refined_rcp(sp);
  float v[8][4];
  float denom;
  attn_e_phase(qq + (size_t)bh * 32768, qk + (size_t)bh * 32768, rb, pref, pla, v, red, denom);
  float rdn = refined_rcp(denom);
  int t = threadIdx.x, lane = t & 63, w = t >> 6, l15 = lane & 15, kg = lane >> 4;
#pragma unroll
  for (int i = 0; i < 8; ++i) {
    uint32_t packed = 0;
#pragma unroll
    for (int r = 0; r < 4; ++r) {
      float sm32 = fdiv_m(v[i][r] * 32768.0f, denom, rdn);
      float q15 = clamp3(rintf(sm32), -32768.0f, 32767.0f);
      float pv = q15 * (1.0f / 32768.0f);
      int qp = (int)clamp3(rintf(fdiv_m(pv, sp, rsp)), -QMAXF, QMAXF);
      packed |= (uint32_t)(qp & 255) << (8 * r);
    }
    *(uint32_t*)&Ps[l15][(w * 8 + i) * 16 + kg * 4] = packed;
  }
  __syncthreads();
  attn_pv_tail(vT, Ps, scal, ctx, rb, bh, sp);
}

// ---------------- collapsed ctx double-quant + qbias_o (R9-proven) ----------------

__global__ __launch_bounds__(256) void ctx_q12_plus(const float4* __restrict__ ctx, int* __restrict__ q2o,
                                                    const float* __restrict__ bo, float* __restrict__ qbo,
                                                    unsigned* __restrict__ scal) {
  int blk = blockIdx.x;
  float s1 = qscale(scal, S_CTX);
  float ctxq1max = 127.0f * s1;
  if (blk < 3072) {
    float rs1 = refined_rcp(s1);
    int i = blk * 256 + threadIdx.x;
    float4 c = ctx[i];
    int q0 = (int)clamp3(rintf(fdiv_m(c.x, s1, rs1)), -QMAXF, QMAXF);
    int q1 = (int)clamp3(rintf(fdiv_m(c.y, s1, rs1)), -QMAXF, QMAXF);
    int q2 = (int)clamp3(rintf(fdiv_m(c.z, s1, rs1)), -QMAXF, QMAXF);
    int q3 = (int)clamp3(rintf(fdiv_m(c.w, s1, rs1)), -QMAXF, QMAXF);
    q2o[i] = (q0 & 255) | ((q1 & 255) << 8) | ((q2 & 255) << 16) | ((q3 & 255) << 24);
  } else {
    if (blk == 3072 && threadIdx.x == 0) scal[S_CTXQ1] = __float_as_uint(ctxq1max);
    int j = (blk - 3072) * 256 + threadIdx.x;
    if (j < 768) {
      float in_scale = ctxq1max / QMAXF;   // no clamp (reference)
      float w_scale = __uint_as_float(scal[S_WO]) / QMAXF;
      float bias_scale = in_scale * w_scale;
      float tmax = __uint_as_float(scal[S_BO]) / bias_scale;
      float st = fmaxf(tmax / QMAXF, 1e-8f);
      float tv = bo[j] / bias_scale;
      float qv = fminf(fmaxf(rintf(tv / st), -127.0f), 127.0f) * st;
      qbo[j] = qv * bias_scale;
    }
  }
}

// ---------------- host: PLA build (replicates np.polyfit degree-1 LS in f64) ----------------

static void build_pla(PLA& p) {
  double xs[1001], ys[1001];
  double step = 10.0 / 1000.0;
  for (int j = 0; j <= 1000; ++j) xs[j] = (double)j * step + (-10.0);
  xs[1000] = 0.0;
  for (int j = 0; j <= 1000; ++j) ys[j] = exp(xs[j]);
  double estep = 10.0 / 12.0;
  for (int i = 0; i < 12; ++i) {
    double a = (double)i * estep + (-10.0);
    double bb = (i + 1 == 12) ? 0.0 : (double)(i + 1) * estep + (-10.0);
    double n = 0, Sx = 0, Sy = 0, Sxx = 0, Sxy = 0;
    for (int j = 0; j <= 1000; ++j) {
      if (xs[j] >= a && xs[j] <= bb) {
        double x = xs[j], y = ys[j];
        n += 1.0; Sx += x; Sy += y; Sxx += x * x; Sxy += x * y;
      }
    }
    double det = n * Sxx - Sx * Sx;
    p.m[i] = (float)((n * Sxy - Sx * Sy) / det);
    p.c[i] = (float)((Sxx * Sy - Sx * Sxy) / det);
    p.a[i] = (float)a;
  }
}

// ---------------- launch ----------------

extern "C" void kernel_launch(void* const* d_in, const int* in_sizes, int n_in,
                              void* d_out, int out_size, void* d_ws, size_t ws_size,
                              hipStream_t stream) {
  const float* X  = (const float*)d_in[0];
  const float* Wq = (const float*)d_in[1];
  const float* bq = (const float*)d_in[2];
  const float* Wk = (const float*)d_in[3];
  const float* bk = (const float*)d_in[4];
  const float* Wv = (const float*)d_in[5];
  const float* bv = (const float*)d_in[6];
  const float* Wo = (const float*)d_in[7];
  const float* bo = (const float*)d_in[8];
  float* out = (float*)d_out;
  (void)n_in; (void)in_sizes; (void)out_size;

  PLA pla;
  build_pla(pla);

  const size_t NX = 8 * 512 * 768;   // 3145728
  const size_t NW = 768 * 768;       // 589824
  const size_t Q15_BYTES = 3072ull * 16384;  // 48 MiB

  uint8_t* ws = (uint8_t*)d_ws;
  size_t off = 0;
  auto alloc = [&](size_t bytes) -> void* {
    void* p = ws + off;
    off += (bytes + 255) & ~(size_t)255;
    return p;
  };

  unsigned* scal = (unsigned*)alloc(256);
  int8_t* qWq = (int8_t*)alloc(NW);
  int8_t* qWk = (int8_t*)alloc(NW);
  int8_t* qWv = (int8_t*)alloc(NW);
  int8_t* qWo = (int8_t*)alloc(NW);
  float* qbq = (float*)alloc(768 * 4);
  float* qbk = (float*)alloc(768 * 4);
  float* qbv = (float*)alloc(768 * 4);
  float* qbo = (float*)alloc(768 * 4);
  int8_t* qX = (int8_t*)alloc(NX);       // reused as qctx2
  int8_t* qctx2 = qX;

  size_t fixed = off;
  size_t need_fast = fixed + Q15_BYTES + (4 * NX) + NX + 512;
  bool fast = ws_size >= need_fast;

  hipMemsetAsync(scal, 0, 256, stream);

  if (fast) {
    uint8_t* D = (uint8_t*)alloc(Q15_BYTES);        // Yq|Yk|Yv then q15
    float* Yq = (float*)D;
    float* Yk = (float*)(D + NX * 4);
    float* Yv = (float*)(D + 2 * NX * 4);
    int* q15buf = (int*)D;
    uint8_t* E = (uint8_t*)alloc(4 * NX);           // qq|qk then ctx
    int8_t* qq = (int8_t*)E;
    int8_t* qk = (int8_t*)(E + NX);
    float* ctx = (float*)E;
    int8_t* qvT = (int8_t*)alloc(NX);

    maxabs_all<<<1604, 256, 0, stream>>>((const float4*)X, (const float4*)Wq, (const float4*)Wk,
                                         (const float4*)Wv, (const float4*)Wo, bq, bk, bv, bo, scal);
    quant_all<<<1609, 256, 0, stream>>>((const float4*)X, (int*)qX,
                                        (const float4*)Wq, (const float4*)Wk, (const float4*)Wv, (const float4*)Wo,
                                        (int*)qWq, (int*)qWk, (int*)qWv, (int*)qWo,
                                        bq, bk, bv, qbq, qbk, qbv, scal);
    gemm_qkv<<<dim3(12, 32, 3), 256, 0, stream>>>(qX, qWq, qWk, qWv, qbq, qbk, qbv, Yq, Yk, Yv, scal);
    quant_heads_all<<<6912, 256, 0, stream>>>(Yq, (int*)qq, Yk, (int*)qk, Yv, qvT, scal);
    attn_pass1<<<3072, 256, 0, stream>>>(qq, qk, q15buf, scal, pla);         // q15 overwrites Y (dead)
    attn_pass2_load<<<3072, 256, 0, stream>>>(q15buf, qvT, scal, ctx, pla);  // ctx overwrites qq/qk (dead)
    ctx_q12_plus<<<3075, 256, 0, stream>>>((const float4*)ctx, (int*)qctx2, bo, qbo, scal);
    gemm_proj<<<dim3(12, 32), 256, 0, stream>>>(qctx2, qWo, out, qbo, scal, S_CTXQ1, S_WO, -1);
  } else {
    float* Y = (float*)alloc(NX * 4);               // then ctx
    float* ctx = Y;
    int8_t* qq = (int8_t*)alloc(NX);
    int8_t* qk = (int8_t*)alloc(NX);
    int8_t* qvT = (int8_t*)alloc(NX);

    maxabs_all<<<1604, 256, 0, stream>>>((const float4*)X, (const float4*)Wq, (const float4*)Wk,
                                         (const float4*)Wv, (const float4*)Wo, bq, bk, bv, bo, scal);
    quant_all<<<1609, 256, 0, stream>>>((const float4*)X, (int*)qX,
                                        (const float4*)Wq, (const float4*)Wk, (const float4*)Wv, (const float4*)Wo,
                                        (int*)qWq, (int*)qWk, (int*)qWv, (int*)qWo,
                                        bq, bk, bv, qbq, qbk, qbv, scal);
    gemm_proj<<<dim3(12, 32), 256, 0, stream>>>(qX, qWq, Y, qbq, scal, S_X, S_WQ, S_YQ);
    quant_heads_qk<<<3072, 256, 0, stream>>>(Y, (int*)qq, scal, S_YQ);
    gemm_proj<<<dim3(12, 32), 256, 0, stream>>>(qX, qWk, Y, qbk, scal, S_X, S_WK, S_YK);
    quant_heads_qk<<<3072, 256, 0, stream>>>(Y, (int*)qk, scal, S_YK);
    gemm_proj<<<dim3(12, 32), 256, 0, stream>>>(qX, qWv, Y, qbv, scal, S_X, S_WV, S_YV);
    quant_heads_v<<<768, 256, 0, stream>>>(Y, qvT, scal);
    attn_pass1<<<3072, 256, 0, stream>>>(qq, qk, (int*)nullptr, scal, pla);
    attn_pass2_recompute<<<3072, 256, 0, stream>>>(qq, qk, qvT, scal, ctx, pla);
    ctx_q12_plus<<<3075, 256, 0, stream>>>((const float4*)ctx, (int*)qctx2, bo, qbo, scal);
    gemm_proj<<<dim3(12, 32), 256, 0, stream>>>(qctx2, qWo, out, qbo, scal, S_CTXQ1, S_WO, -1);
  }
}

// Round 12
// 174.556 us; speedup vs baseline: 1.0096x; 1.0096x over previous
//
#include <hip/hip_runtime.h>
#include <cstdint>
#include <cmath>
#include <cstddef>

#pragma clang fp contract(off)

#define QMAXF 127.0f

typedef int i32x4 __attribute__((ext_vector_type(4)));

enum {
  S_X = 0, S_WQ, S_WK, S_WV, S_WO, S_BQ, S_BK, S_BV, S_BO,
  S_YQ, S_YK, S_YV, S_CTX, S_CTXQ1, S_DMIN, S_PAD
};

struct PLA { float m[12]; float c[12]; float a[12]; };

#define GLOAD_LDS16(gsrc, ldst) \
  __builtin_amdgcn_global_load_lds((const __attribute__((address_space(1))) void*)(gsrc), \
                                   (__attribute__((address_space(3))) void*)(ldst), 16, 0, 0)

// ---------------- device helpers ----------------

__device__ __forceinline__ float qscale(const unsigned* scal, int slot) {
  // reference: scale = max(maxabs / 127.0, 1e-8)
  return fmaxf(__uint_as_float(scal[slot]) / QMAXF, 1e-8f);
}

// Markstein correctly-rounded division with hoisted refined reciprocal (validated R6/R8).
__device__ __forceinline__ float refined_rcp(float d) {
  float rd = __builtin_amdgcn_rcpf(d);
  return fmaf(fmaf(-d, rd, 1.0f), rd, rd);
}
__device__ __forceinline__ float fdiv_m(float v, float d, float rd) {
  float q0 = v * rd;
  float r = fmaf(-d, q0, v);
  return fmaf(r, rd, q0);
}

__device__ __forceinline__ void block_atomic_maxf(float v, unsigned* slot) {
  for (int off = 32; off > 0; off >>= 1) v = fmaxf(v, __shfl_xor(v, off, 64));
  __shared__ float red4[4];
  int lane = threadIdx.x & 63, w = threadIdx.x >> 6;
  if (lane == 0) red4[w] = v;
  __syncthreads();
  if (threadIdx.x == 0)
    atomicMax(slot, __float_as_uint(fmaxf(fmaxf(red4[0], red4[1]), fmaxf(red4[2], red4[3]))));
}

__device__ __forceinline__ int qpack4(float a0, float a1, float a2, float a3, float s) {
  int i0 = (int)fminf(fmaxf(rintf(a0 / s), -QMAXF), QMAXF);
  int i1 = (int)fminf(fmaxf(rintf(a1 / s), -QMAXF), QMAXF);
  int i2 = (int)fminf(fmaxf(rintf(a2 / s), -QMAXF), QMAXF);
  int i3 = (int)fminf(fmaxf(rintf(a3 / s), -QMAXF), QMAXF);
  return (i0 & 255) | ((i1 & 255) << 8) | ((i2 & 255) << 16) | ((i3 & 255) << 24);
}

__device__ __forceinline__ float fabs4max(float4 v) {
  return fmaxf(fmaxf(fabsf(v.x), fabsf(v.y)), fmaxf(fabsf(v.z), fabsf(v.w)));
}

// ---------------- fused maxabs: X + 4 weights + 4 biases ----------------

__global__ __launch_bounds__(256) void maxabs_all(const float4* __restrict__ X,
                                                  const float4* __restrict__ w0, const float4* __restrict__ w1,
                                                  const float4* __restrict__ w2, const float4* __restrict__ w3,
                                                  const float* __restrict__ b0, const float* __restrict__ b1,
                                                  const float* __restrict__ b2, const float* __restrict__ b3,
                                                  unsigned* __restrict__ scal) {
  int blk = blockIdx.x, t = threadIdx.x;
  float m = 0.0f;
  unsigned* slot;
  if (blk < 1024) {
    int i = blk * 256 + t;
#pragma unroll
    for (int k = 0; k < 3; ++k) m = fmaxf(m, fabs4max(X[i + k * 262144]));
    slot = scal + S_X;
  } else if (blk < 1600) {
    int which = (blk - 1024) / 144, j = (blk - 1024) % 144;
    const float4* p = which == 0 ? w0 : which == 1 ? w1 : which == 2 ? w2 : w3;
    int i = j * 256 + t;
#pragma unroll
    for (int k = 0; k < 4; ++k) m = fmaxf(m, fabs4max(p[i + k * 36864]));
    slot = scal + S_WQ + which;
  } else {
    int which = blk - 1600;
    const float* p = which == 0 ? b0 : which == 1 ? b1 : which == 2 ? b2 : b3;
    for (int i = t; i < 768; i += 256) m = fmaxf(m, fabsf(p[i]));
    slot = scal + S_BQ + which;
  }
  block_atomic_maxf(m, slot);
}

// ---------------- fused quant: X + 4 weights + qbias(q,k,v) ----------------

__device__ __forceinline__ void qbias_body(const float* __restrict__ b, float* __restrict__ qb,
                                           const unsigned* __restrict__ scal, int slotX, int slotW, int slotB, int j) {
  if (j >= 768) return;
  float in_scale = __uint_as_float(scal[slotX]) / QMAXF;   // no clamp (reference)
  float w_scale  = __uint_as_float(scal[slotW]) / QMAXF;
  float bias_scale = in_scale * w_scale;
  float tmax = __uint_as_float(scal[slotB]) / bias_scale;
  float st = fmaxf(tmax / QMAXF, 1e-8f);
  float t = b[j] / bias_scale;
  float qv = fminf(fmaxf(rintf(t / st), -127.0f), 127.0f) * st;
  qb[j] = qv * bias_scale;
}

__global__ __launch_bounds__(256) void quant_all(const float4* __restrict__ X, int* __restrict__ qX,
                                                 const float4* __restrict__ w0, const float4* __restrict__ w1,
                                                 const float4* __restrict__ w2, const float4* __restrict__ w3,
                                                 int* __restrict__ o0, int* __restrict__ o1,
                                                 int* __restrict__ o2, int* __restrict__ o3,
                                                 const float* __restrict__ bq, const float* __restrict__ bk,
                                                 const float* __restrict__ bv,
                                                 float* __restrict__ qbq, float* __restrict__ qbk,
                                                 float* __restrict__ qbv,
                                                 const unsigned* __restrict__ scal) {
  int blk = blockIdx.x, t = threadIdx.x;
  if (blk < 1024) {
    float s = qscale(scal, S_X);
    int i = blk * 256 + t;
#pragma unroll
    for (int k = 0; k < 3; ++k) {
      float4 v = X[i + k * 262144];
      qX[i + k * 262144] = qpack4(v.x, v.y, v.z, v.w, s);
    }
  } else if (blk < 1600) {
    int which = (blk - 1024) / 144, j = (blk - 1024) % 144;
    const float4* p = which == 0 ? w0 : which == 1 ? w1 : which == 2 ? w2 : w3;
    int* o = which == 0 ? o0 : which == 1 ? o1 : which == 2 ? o2 : o3;
    float s = qscale(scal, S_WQ + which);
    int i = j * 256 + t;
#pragma unroll
    for (int k = 0; k < 4; ++k) {
      float4 v = p[i + k * 36864];
      o[i + k * 36864] = qpack4(v.x, v.y, v.z, v.w, s);
    }
  } else {
    int proj = (blk - 1600) / 3, part = (blk - 1600) % 3;
    int j = part * 256 + t;
    const float* b = proj == 0 ? bq : proj == 1 ? bk : bv;
    float* qb = proj == 0 ? qbq : proj == 1 ? qbk : qbv;
    qbias_body(b, qb, scal, S_X, S_WQ + proj, S_BQ + proj, j);
  }
}

// ---------------- LDS-staged MFMA int8 GEMM (proven R5/R6 structure) ----------------

__device__ __forceinline__ void gemm_body(const int8_t* __restrict__ A, const int8_t* __restrict__ Bm,
                                          float* __restrict__ C, const float* __restrict__ bias,
                                          unsigned* __restrict__ scal, int slotA, int slotB, int maxslot) {
  __shared__ int8_t Al[16384];
  __shared__ int8_t Bl[8192];
  int t = threadIdx.x, lane = t & 63, w = t >> 6, l15 = lane & 15, kg4 = lane >> 4;
  int bm = blockIdx.y * 128, bn = blockIdx.x * 64;
  float sAB = qscale(scal, slotA) * qscale(scal, slotB);
  int srow = t >> 3, scol = (t & 7) * 16;
  int ssw = scol ^ ((srow & 7) << 4);
  i32x4 acc[2][4];
#pragma unroll
  for (int rt = 0; rt < 2; ++rt)
#pragma unroll
    for (int ct = 0; ct < 4; ++ct)
#pragma unroll
      for (int r = 0; r < 4; ++r) acc[rt][ct][r] = 0;

  for (int kt = 0; kt < 6; ++kt) {
    int kc = kt * 128;
#pragma unroll
    for (int j = 0; j < 4; ++j) {
      int r = j * 32 + srow;
      GLOAD_LDS16(A + (size_t)(bm + r) * 768 + kc + ssw, Al + r * 128 + scol);
    }
#pragma unroll
    for (int j = 0; j < 2; ++j) {
      int r = j * 32 + srow;
      GLOAD_LDS16(Bm + (size_t)(bn + r) * 768 + kc + ssw, Bl + r * 128 + scol);
    }
    __syncthreads();
#pragma unroll
    for (int kg = 0; kg < 2; ++kg) {
      int kcol = kg * 64 + kg4 * 16;
      i32x4 af[2], bf[4];
#pragma unroll
      for (int rt = 0; rt < 2; ++rt) {
        int ar = w * 32 + rt * 16 + l15;
        af[rt] = *(const i32x4*)(Al + ar * 128 + (kcol ^ ((ar & 7) << 4)));
      }
#pragma unroll
      for (int ct = 0; ct < 4; ++ct) {
        int br = ct * 16 + l15;
        bf[ct] = *(const i32x4*)(Bl + br * 128 + (kcol ^ ((br & 7) << 4)));
      }
#pragma unroll
      for (int rt = 0; rt < 2; ++rt)
#pragma unroll
        for (int ct = 0; ct < 4; ++ct)
          acc[rt][ct] = __builtin_amdgcn_mfma_i32_16x16x64_i8(af[rt], bf[ct], acc[rt][ct], 0, 0, 0);
    }
    __syncthreads();
  }
  float am = 0.0f;
#pragma unroll
  for (int rt = 0; rt < 2; ++rt)
#pragma unroll
    for (int ct = 0; ct < 4; ++ct) {
      int col = bn + ct * 16 + l15;
      float bv = bias[col];
#pragma unroll
      for (int r = 0; r < 4; ++r) {
        int row = bm + w * 32 + rt * 16 + kg4 * 4 + r;
        float v = (float)acc[rt][ct][r] * sAB;
        float yv = v + bv;
        C[(size_t)row * 768 + col] = yv;
        am = fmaxf(am, fabsf(yv));
      }
    }
  if (maxslot >= 0) block_atomic_maxf(am, scal + maxslot);
}

__global__ __launch_bounds__(256) void gemm_qkv(const int8_t* __restrict__ qX,
                                                const int8_t* __restrict__ qWq, const int8_t* __restrict__ qWk,
                                                const int8_t* __restrict__ qWv,
                                                const float* __restrict__ qbq, const float* __restrict__ qbk,
                                                const float* __restrict__ qbv,
                                                float* __restrict__ Yq, float* __restrict__ Yk, float* __restrict__ Yv,
                                                unsigned* __restrict__ scal) {
  int z = blockIdx.z;
  const int8_t* Bm = z == 0 ? qWq : z == 1 ? qWk : qWv;
  const float* bias = z == 0 ? qbq : z == 1 ? qbk : qbv;
  float* C = z == 0 ? Yq : z == 1 ? Yk : Yv;
  gemm_body(qX, Bm, C, bias, scal, S_X, S_WQ + z, S_YQ + z);
}

__global__ __launch_bounds__(256) void gemm_proj(const int8_t* __restrict__ A, const int8_t* __restrict__ Bm,
                                                 float* __restrict__ C, const float* __restrict__ bias,
                                                 unsigned* __restrict__ scal, int slotA, int slotB, int maxslot) {
  gemm_body(A, Bm, C, bias, scal, slotA, slotB, maxslot);
}

// ---------------- head re-layout + quant ----------------

__device__ __forceinline__ void qheads_qk_body(const float* __restrict__ Y, int* __restrict__ q,
                                               const unsigned* __restrict__ scal, int slot, int i) {
  float s = qscale(scal, slot);
  int d0 = (i & 15) * 4;
  int sI = (i >> 4) & 511;
  int bh = i >> 13;
  int h = bh % 12, b = bh / 12;
  const float* src = Y + ((size_t)(b * 512 + sI)) * 768 + h * 64 + d0;
  float4 v = *(const float4*)src;
  q[i] = qpack4(v.x, v.y, v.z, v.w, s);
}

__device__ __forceinline__ void qheads_v_body(const float* __restrict__ Y, int8_t* __restrict__ q,
                                              const unsigned* __restrict__ scal, int blkv) {
  __shared__ int8_t T[64][68];
  int bh = blkv >> 3, sb = blkv & 7;
  int b = bh / 12, h = bh % 12;
  float s = qscale(scal, S_YV);
  int d = threadIdx.x & 63, sl = threadIdx.x >> 6;
#pragma unroll
  for (int i = 0; i < 16; ++i) {
    int s_local = i * 4 + sl;
    float y = Y[((size_t)(b * 512 + sb * 64 + s_local)) * 768 + h * 64 + d];
    float tq = fminf(fmaxf(rintf(y / s), -QMAXF), QMAXF);
    T[d][s_local] = (int8_t)tq;
  }
  __syncthreads();
  int s4 = (threadIdx.x & 15) * 4, dl = threadIdx.x >> 4;
#pragma unroll
  for (int i = 0; i < 4; ++i) {
    int d_ = i * 16 + dl;
    int packed = (T[d_][s4] & 255) | ((T[d_][s4 + 1] & 255) << 8) |
                 ((T[d_][s4 + 2] & 255) << 16) | ((T[d_][s4 + 3] & 255) << 24);
    *(int*)(q + (size_t)bh * 32768 + (size_t)d_ * 512 + sb * 64 + s4) = packed;
  }
}

__global__ __launch_bounds__(256) void quant_heads_all(const float* __restrict__ Yq, int* __restrict__ qq,
                                                       const float* __restrict__ Yk, int* __restrict__ qk,
                                                       const float* __restrict__ Yv, int8_t* __restrict__ qvT,
                                                       const unsigned* __restrict__ scal) {
  int blk = blockIdx.x;
  if (blk < 3072)      qheads_qk_body(Yq, qq, scal, S_YQ, blk * 256 + threadIdx.x);
  else if (blk < 6144) qheads_qk_body(Yk, qk, scal, S_YK, (blk - 3072) * 256 + threadIdx.x);
  else                 qheads_v_body(Yv, qvT, scal, blk - 6144);
}

__global__ __launch_bounds__(256) void quant_heads_qk(const float* __restrict__ Y, int* __restrict__ q,
                                                      const unsigned* __restrict__ scal, int slot) {
  qheads_qk_body(Y, q, scal, slot, blockIdx.x * 256 + threadIdx.x);
}
__global__ __launch_bounds__(256) void quant_heads_v(const float* __restrict__ Y, int8_t* __restrict__ q,
                                                     const unsigned* __restrict__ scal) {
  qheads_v_body(Y, q, scal, blockIdx.x);
}

// ---------------- attention e-phase (R6/R10-proven 4-wave version) ----------------

__device__ __forceinline__ void attn_e_phase(const int8_t* __restrict__ qbase,
                                             const int8_t* __restrict__ kbase,
                                             int rb, float pref, const PLA& pla,
                                             float (&v)[8][4], float (*red)[16], float& denom) {
  __shared__ float2 ae2[11];   // (a[i], a[i+1])
  __shared__ float2 mcs[11];   // (m[i], c[i])
  int t = threadIdx.x, lane = t & 63, w = t >> 6, l15 = lane & 15, kg = lane >> 4;
  if (t < 11) {
    ae2[t] = make_float2(pla.a[t], pla.a[t + 1]);
    mcs[t] = make_float2(pla.m[t], pla.c[t]);
  }
  i32x4 zero = {0, 0, 0, 0};
  i32x4 qf = *(const i32x4*)(qbase + (size_t)(rb * 16 + l15) * 64 + kg * 16);
  i32x4 acc[8];
#pragma unroll
  for (int i = 0; i < 8; ++i) {
    i32x4 kf = *(const i32x4*)(kbase + (size_t)((w * 8 + i) * 16 + l15) * 64 + kg * 16);
    acc[i] = __builtin_amdgcn_mfma_i32_16x16x64_i8(kf, qf, zero, 0, 0, 0);
  }
  float mx = -3.4e38f;
#pragma unroll
  for (int i = 0; i < 8; ++i)
#pragma unroll
    for (int r = 0; r < 4; ++r) {
      v[i][r] = (float)acc[i][r] * pref;
      mx = fmaxf(mx, v[i][r]);
    }
  mx = fmaxf(mx, __shfl_xor(mx, 16, 64));
  mx = fmaxf(mx, __shfl_xor(mx, 32, 64));
  if (lane < 16) red[w][l15] = mx;
  __syncthreads();                     // also covers ae2/mcs init
  float gm = fmaxf(fmaxf(red[0][l15], red[1][l15]), fmaxf(red[2][l15], red[3][l15]));
  __syncthreads();
  float s = 0.0f;
#pragma unroll
  for (int i = 0; i < 8; ++i)
#pragma unroll
    for (int r = 0; r < 4; ++r) {
      float x = v[i][r] - gm;
      float sh = rintf(x * 67108864.0f);
      sh = fmaxf(sh, -671088640.0f);
      sh = fminf(sh, 0.0f);
      float xc = sh * (1.0f / 67108864.0f);
      float tf = (xc + 10.0f) * 1.2f;
      int i0 = (int)tf;
      i0 = i0 > 10 ? 10 : i0;
      float2 ee = ae2[i0];
      int idx = i0 + ((i0 < 10 && xc >= ee.y) ? 1 : 0) - ((xc < ee.x) ? 1 : 0);
      float2 mc = mcs[idx];
      float e = mc.x * xc;   // no fma: contract off
      e = e + mc.y;
      v[i][r] = e;
      s += e;
    }
  s += __shfl_xor(s, 16, 64);
  s += __shfl_xor(s, 32, 64);
  if (lane < 16) red[w][l15] = s;
  __syncthreads();
  denom = (((red[0][l15] + red[1][l15]) + red[2][l15]) + red[3][l15]) + 1e-9f;
  __syncthreads();   // protect red reuse by subsequent calls
}

// ---------------- pass1: R6 4-wave structure + NONTEMPORAL thread-major dwordx4 q15 stores ----
// q15 is a 48MB write-once/read-once stream that can never fit L2 (32MB) -- nt stores avoid
// dirtying L2 and evicting the K/V working set (pass1's 14MB FETCH shows K reuse via L2).

__global__ __launch_bounds__(256) void attn_pass1(const int8_t* __restrict__ qq,
                                                  const int8_t* __restrict__ qk,
                                                  int* __restrict__ q15w,
                                                  unsigned* __restrict__ scal, PLA pla) {
  __shared__ float red[4][16];
  int rb = blockIdx.x & 31, bh = blockIdx.x >> 5;
  float pref = (qscale(scal, S_YQ) * qscale(scal, S_YK)) * 0.125f;
  float v[8][4];
  float denom;
  attn_e_phase(qq + (size_t)bh * 32768, qk + (size_t)bh * 32768, rb, pref, pla, v, red, denom);
  int t = threadIdx.x;
  if (q15w) {
    float rdn = refined_rcp(denom);
    int d[16];
#pragma unroll
    for (int i = 0; i < 8; ++i) {
      int q15i[4];
#pragma unroll
      for (int r = 0; r < 4; ++r) {
        float sm32 = fdiv_m(v[i][r] * 32768.0f, denom, rdn);
        q15i[r] = (int)fminf(fmaxf(rintf(sm32), -32768.0f), 32767.0f);
      }
      d[i * 2]     = (q15i[0] & 0xffff) | (q15i[1] << 16);
      d[i * 2 + 1] = (q15i[2] & 0xffff) | (q15i[3] << 16);
    }
    i32x4* q15v = (i32x4*)(q15w + (size_t)blockIdx.x * 4096);
#pragma unroll
    for (int j = 0; j < 4; ++j) {
      i32x4 pk = { d[4 * j], d[4 * j + 1], d[4 * j + 2], d[4 * j + 3] };
      __builtin_nontemporal_store(pk, &q15v[j * 256 + t]);
    }
  }
  if (t < 64) {
    float dm = denom;
    dm = fminf(dm, __shfl_xor(dm, 1, 64));
    dm = fminf(dm, __shfl_xor(dm, 2, 64));
    dm = fminf(dm, __shfl_xor(dm, 4, 64));
    dm = fminf(dm, __shfl_xor(dm, 8, 64));
    if (t == 0) atomicMax(scal + S_DMIN, 0x7f800000u - __float_as_uint(dm));
  }
}

__device__ __forceinline__ float derive_sp(const unsigned* scal, const PLA& pla) {
  float dmin = __uint_as_float(0x7f800000u - scal[S_DMIN]);
  float smm = pla.c[10] / dmin;
  float q15m = fminf(fmaxf(rintf(smm * 32768.0f), -32768.0f), 32767.0f);
  return fmaxf((q15m * (1.0f / 32768.0f)) / QMAXF, 1e-8f);
}

__device__ __forceinline__ void attn_pv_tail(const int8_t* __restrict__ vT, int8_t (*Ps)[528],
                                             unsigned* __restrict__ scal, float* __restrict__ ctx,
                                             int rb, int bh, float sp) {
  int t = threadIdx.x, lane = t & 63, w = t >> 6, l15 = lane & 15, kg = lane >> 4;
  int b = bh / 12, h = bh % 12;
  float sv = qscale(scal, S_YV);
  i32x4 pacc = {0, 0, 0, 0};
  const int8_t* vbase = vT + (size_t)bh * 32768 + (size_t)(w * 16 + l15) * 512;
#pragma unroll
  for (int ks = 0; ks < 8; ++ks) {
    i32x4 pf = *(const i32x4*)&Ps[l15][ks * 64 + kg * 16];
    i32x4 vf = *(const i32x4*)(vbase + ks * 64 + kg * 16);
    pacc = __builtin_amdgcn_mfma_i32_16x16x64_i8(pf, vf, pacc, 0, 0, 0);
  }
  float spv = sp * sv;
  float am = 0.0f;
#pragma unroll
  for (int r = 0; r < 4; ++r) {
    int srow = rb * 16 + kg * 4 + r;
    float val = (float)pacc[r] * spv;
    ctx[((size_t)(b * 512 + srow)) * 768 + h * 64 + w * 16 + l15] = val;
    am = fmaxf(am, fabsf(val));
  }
  block_atomic_maxf(am, scal + S_CTX);
}

__global__ __launch_bounds__(256) void attn_pass2_load(const int* __restrict__ q15r,
                                                       const int8_t* __restrict__ vT,
                                                       unsigned* __restrict__ scal,
                                                       float* __restrict__ ctx, PLA pla) {
  __shared__ alignas(16) int8_t Ps[16][528];
  int rb = blockIdx.x & 31, bh = blockIdx.x >> 5;
  float sp = derive_sp(scal, pla);
  float rsp = refined_rcp(sp);
  int t = threadIdx.x, lane = t & 63, w = t >> 6, l15 = lane & 15, kg = lane >> 4;
  const i32x4* q15v = (const i32x4*)(q15r + (size_t)blockIdx.x * 4096);
  int d[16];
#pragma unroll
  for (int j = 0; j < 4; ++j) {
    i32x4 pk = __builtin_nontemporal_load(&q15v[j * 256 + t]);
    d[4 * j] = pk[0]; d[4 * j + 1] = pk[1]; d[4 * j + 2] = pk[2]; d[4 * j + 3] = pk[3];
  }
#pragma unroll
  for (int i = 0; i < 8; ++i) {
    int u01 = d[i * 2], u23 = d[i * 2 + 1];
    int q15i[4] = { (int)(short)(u01 & 0xffff), u01 >> 16,
                    (int)(short)(u23 & 0xffff), u23 >> 16 };
    uint32_t packed = 0;
#pragma unroll
    for (int r = 0; r < 4; ++r) {
      float pv = (float)q15i[r] * (1.0f / 32768.0f);
      int qp = (int)fminf(fmaxf(rintf(fdiv_m(pv, sp, rsp)), -QMAXF), QMAXF);
      packed |= (uint32_t)(qp & 255) << (8 * r);
    }
    *(uint32_t*)&Ps[l15][(w * 8 + i) * 16 + kg * 4] = packed;
  }
  __syncthreads();
  attn_pv_tail(vT, Ps, scal, ctx, rb, bh, sp);
}

// fallback pass2: recompute e-phase, quantize, PV (R6 path)
__global__ __launch_bounds__(256) void attn_pass2_recompute(const int8_t* __restrict__ qq,
                                                            const int8_t* __restrict__ qk,
                                                            const int8_t* __restrict__ vT,
                                                            unsigned* __restrict__ scal,
                                                            float* __restrict__ ctx, PLA pla) {
  __shared__ float red[4][16];
  __shared__ alignas(16) int8_t Ps[16][528];
  int rb = blockIdx.x & 31, bh = blockIdx.x >> 5;
  float pref = (qscale(scal, S_YQ) * qscale(scal, S_YK)) * 0.125f;
  float sp = derive_sp(scal, pla);
  float rsp = refined_rcp(sp);
  float v[8][4];
  float denom;
  attn_e_phase(qq + (size_t)bh * 32768, qk + (size_t)bh * 32768, rb, pref, pla, v, red, denom);
  float rdn = refined_rcp(denom);
  int t = threadIdx.x, lane = t & 63, w = t >> 6, l15 = lane & 15, kg = lane >> 4;
#pragma unroll
  for (int i = 0; i < 8; ++i) {
    uint32_t packed = 0;
#pragma unroll
    for (int r = 0; r < 4; ++r) {
      float sm32 = fdiv_m(v[i][r] * 32768.0f, denom, rdn);
      float q15 = fminf(fmaxf(rintf(sm32), -32768.0f), 32767.0f);
      float pv = q15 * (1.0f / 32768.0f);
      int qp = (int)fminf(fmaxf(rintf(fdiv_m(pv, sp, rsp)), -QMAXF), QMAXF);
      packed |= (uint32_t)(qp & 255) << (8 * r);
    }
    *(uint32_t*)&Ps[l15][(w * 8 + i) * 16 + kg * 4] = packed;
  }
  __syncthreads();
  attn_pv_tail(vT, Ps, scal, ctx, rb, bh, sp);
}

// ---------------- collapsed ctx double-quant + qbias_o (R9-proven) ----------------
// q2 == q0 identity (R8-proven): with ctxq1max = fl(127*s1), s2 = s1*(1 +- 1ulp), so
// rint(q0*s1/s2) == q0 for |q0|<=127. qctx2 = q0 directly; S_CTXQ1 <- fl(127*s1).

__global__ __launch_bounds__(256) void ctx_q12_plus(const float4* __restrict__ ctx, int* __restrict__ q2o,
                                                    const float* __restrict__ bo, float* __restrict__ qbo,
                                                    unsigned* __restrict__ scal) {
  int blk = blockIdx.x;
  float s1 = qscale(scal, S_CTX);
  float ctxq1max = 127.0f * s1;
  if (blk < 3072) {
    float rs1 = refined_rcp(s1);
    int i = blk * 256 + threadIdx.x;
    float4 c = ctx[i];
    int q0 = (int)fminf(fmaxf(rintf(fdiv_m(c.x, s1, rs1)), -QMAXF), QMAXF);
    int q1 = (int)fminf(fmaxf(rintf(fdiv_m(c.y, s1, rs1)), -QMAXF), QMAXF);
    int q2 = (int)fminf(fmaxf(rintf(fdiv_m(c.z, s1, rs1)), -QMAXF), QMAXF);
    int q3 = (int)fminf(fmaxf(rintf(fdiv_m(c.w, s1, rs1)), -QMAXF), QMAXF);
    q2o[i] = (q0 & 255) | ((q1 & 255) << 8) | ((q2 & 255) << 16) | ((q3 & 255) << 24);
  } else {
    if (blk == 3072 && threadIdx.x == 0) scal[S_CTXQ1] = __float_as_uint(ctxq1max);
    int j = (blk - 3072) * 256 + threadIdx.x;
    if (j < 768) {
      float in_scale = ctxq1max / QMAXF;   // no clamp (reference)
      float w_scale = __uint_as_float(scal[S_WO]) / QMAXF;
      float bias_scale = in_scale * w_scale;
      float tmax = __uint_as_float(scal[S_BO]) / bias_scale;
      float st = fmaxf(tmax / QMAXF, 1e-8f);
      float tv = bo[j] / bias_scale;
      float qv = fminf(fmaxf(rintf(tv / st), -127.0f), 127.0f) * st;
      qbo[j] = qv * bias_scale;
    }
  }
}

// ---------------- host: PLA build (replicates np.polyfit degree-1 LS in f64) ----------------

static void build_pla(PLA& p) {
  double xs[1001], ys[1001];
  double step = 10.0 / 1000.0;
  for (int j = 0; j <= 1000; ++j) xs[j] = (double)j * step + (-10.0);
  xs[1000] = 0.0;
  for (int j = 0; j <= 1000; ++j) ys[j] = exp(xs[j]);
  double estep = 10.0 / 12.0;
  for (int i = 0; i < 12; ++i) {
    double a = (double)i * estep + (-10.0);
    double bb = (i + 1 == 12) ? 0.0 : (double)(i + 1) * estep + (-10.0);
    double n = 0, Sx = 0, Sy = 0, Sxx = 0, Sxy = 0;
    for (int j = 0; j <= 1000; ++j) {
      if (xs[j] >= a && xs[j] <= bb) {
        double x = xs[j], y = ys[j];
        n += 1.0; Sx += x; Sy += y; Sxx += x * x; Sxy += x * y;
      }
    }
    double det = n * Sxx - Sx * Sx;
    p.m[i] = (float)((n * Sxy - Sx * Sy) / det);
    p.c[i] = (float)((Sxx * Sy - Sx * Sxy) / det);
    p.a[i] = (float)a;
  }
}

// ---------------- launch ----------------

extern "C" void kernel_launch(void* const* d_in, const int* in_sizes, int n_in,
                              void* d_out, int out_size, void* d_ws, size_t ws_size,
                              hipStream_t stream) {
  const float* X  = (const float*)d_in[0];
  const float* Wq = (const float*)d_in[1];
  const float* bq = (const float*)d_in[2];
  const float* Wk = (const float*)d_in[3];
  const float* bk = (const float*)d_in[4];
  const float* Wv = (const float*)d_in[5];
  const float* bv = (const float*)d_in[6];
  const float* Wo = (const float*)d_in[7];
  const float* bo = (const float*)d_in[8];
  float* out = (float*)d_out;
  (void)n_in; (void)in_sizes; (void)out_size;

  PLA pla;
  build_pla(pla);

  const size_t NX = 8 * 512 * 768;   // 3145728
  const size_t NW = 768 * 768;       // 589824
  const size_t Q15_BYTES = 3072ull * 16384;  // 48 MiB

  uint8_t* ws = (uint8_t*)d_ws;
  size_t off = 0;
  auto alloc = [&](size_t bytes) -> void* {
    void* p = ws + off;
    off += (bytes + 255) & ~(size_t)255;
    return p;
  };

  unsigned* scal = (unsigned*)alloc(256);
  int8_t* qWq = (int8_t*)alloc(NW);
  int8_t* qWk = (int8_t*)alloc(NW);
  int8_t* qWv = (int8_t*)alloc(NW);
  int8_t* qWo = (int8_t*)alloc(NW);
  float* qbq = (float*)alloc(768 * 4);
  float* qbk = (float*)alloc(768 * 4);
  float* qbv = (float*)alloc(768 * 4);
  float* qbo = (float*)alloc(768 * 4);
  int8_t* qX = (int8_t*)alloc(NX);       // reused as qctx2
  int8_t* qctx2 = qX;

  size_t fixed = off;
  size_t need_fast = fixed + Q15_BYTES + (4 * NX) + NX + 512;
  bool fast = ws_size >= need_fast;

  hipMemsetAsync(scal, 0, 256, stream);

  if (fast) {
    uint8_t* D = (uint8_t*)alloc(Q15_BYTES);        // Yq|Yk|Yv then q15
    float* Yq = (float*)D;
    float* Yk = (float*)(D + NX * 4);
    float* Yv = (float*)(D + 2 * NX * 4);
    int* q15buf = (int*)D;
    uint8_t* E = (uint8_t*)alloc(4 * NX);           // qq|qk then ctx
    int8_t* qq = (int8_t*)E;
    int8_t* qk = (int8_t*)(E + NX);
    float* ctx = (float*)E;
    int8_t* qvT = (int8_t*)alloc(NX);

    maxabs_all<<<1604, 256, 0, stream>>>((const float4*)X, (const float4*)Wq, (const float4*)Wk,
                                         (const float4*)Wv, (const float4*)Wo, bq, bk, bv, bo, scal);
    quant_all<<<1609, 256, 0, stream>>>((const float4*)X, (int*)qX,
                                        (const float4*)Wq, (const float4*)Wk, (const float4*)Wv, (const float4*)Wo,
                                        (int*)qWq, (int*)qWk, (int*)qWv, (int*)qWo,
                                        bq, bk, bv, qbq, qbk, qbv, scal);
    gemm_qkv<<<dim3(12, 32, 3), 256, 0, stream>>>(qX, qWq, qWk, qWv, qbq, qbk, qbv, Yq, Yk, Yv, scal);
    quant_heads_all<<<6912, 256, 0, stream>>>(Yq, (int*)qq, Yk, (int*)qk, Yv, qvT, scal);
    attn_pass1<<<3072, 256, 0, stream>>>(qq, qk, q15buf, scal, pla);         // q15 overwrites Y (dead)
    attn_pass2_load<<<3072, 256, 0, stream>>>(q15buf, qvT, scal, ctx, pla);  // ctx overwrites qq/qk (dead)
    ctx_q12_plus<<<3075, 256, 0, stream>>>((const float4*)ctx, (int*)qctx2, bo, qbo, scal);
    gemm_proj<<<dim3(12, 32), 256, 0, stream>>>(qctx2, qWo, out, qbo, scal, S_CTXQ1, S_WO, -1);
  } else {
    float* Y = (float*)alloc(NX * 4);               // then ctx
    float* ctx = Y;
    int8_t* qq = (int8_t*)alloc(NX);
    int8_t* qk = (int8_t*)alloc(NX);
    int8_t* qvT = (int8_t*)alloc(NX);

    maxabs_all<<<1604, 256, 0, stream>>>((const float4*)X, (const float4*)Wq, (const float4*)Wk,
                                         (const float4*)Wv, (const float4*)Wo, bq, bk, bv, bo, scal);
    quant_all<<<1609, 256, 0, stream>>>((const float4*)X, (int*)qX,
                                        (const float4*)Wq, (const float4*)Wk, (const float4*)Wv, (const float4*)Wo,
                                        (int*)qWq, (int*)qWk, (int*)qWv, (int*)qWo,
                                        bq, bk, bv, qbq, qbk, qbv, scal);
    gemm_proj<<<dim3(12, 32), 256, 0, stream>>>(qX, qWq, Y, qbq, scal, S_X, S_WQ, S_YQ);
    quant_heads_qk<<<3072, 256, 0, stream>>>(Y, (int*)qq, scal, S_YQ);
    gemm_proj<<<dim3(12, 32), 256, 0, stream>>>(qX, qWk, Y, qbk, scal, S_X, S_WK, S_YK);
    quant_heads_qk<<<3072, 256, 0, stream>>>(Y, (int*)qk, scal, S_YK);
    gemm_proj<<<dim3(12, 32), 256, 0, stream>>>(qX, qWv, Y, qbv, scal, S_X, S_WV, S_YV);
    quant_heads_v<<<768, 256, 0, stream>>>(Y, qvT, scal);
    attn_pass1<<<3072, 256, 0, stream>>>(qq, qk, (int*)nullptr, scal, pla);
    attn_pass2_recompute<<<3072, 256, 0, stream>>>(qq, qk, qvT, scal, ctx, pla);
    ctx_q12_plus<<<3075, 256, 0, stream>>>((const float4*)ctx, (int*)qctx2, bo, qbo, scal);
    gemm_proj<<<dim3(12, 32), 256, 0, stream>>>(qctx2, qWo, out, qbo, scal, S_CTXQ1, S_WO, -1);
  }
}

// Round 13
// 159.522 us; speedup vs baseline: 1.1047x; 1.0942x over previous
//
#include <hip/hip_runtime.h>
#include <cstdint>
#include <cmath>
#include <cstddef>

#pragma clang fp contract(off)

#define QMAXF 127.0f

typedef int i32x4 __attribute__((ext_vector_type(4)));

enum {
  S_X = 0, S_WQ, S_WK, S_WV, S_WO, S_BQ, S_BK, S_BV, S_BO,
  S_YQ, S_YK, S_YV, S_CTX, S_CTXQ1, S_DMIN, S_PAD
};

struct PLA { float m[12]; float c[12]; float a[12]; };

#define GLOAD_LDS16(gsrc, ldst) \
  __builtin_amdgcn_global_load_lds((const __attribute__((address_space(1))) void*)(gsrc), \
                                   (__attribute__((address_space(3))) void*)(ldst), 16, 0, 0)

// ---------------- device helpers ----------------

__device__ __forceinline__ float qscale(const unsigned* scal, int slot) {
  // reference: scale = max(maxabs / 127.0, 1e-8)
  return fmaxf(__uint_as_float(scal[slot]) / QMAXF, 1e-8f);
}

// Markstein correctly-rounded division with hoisted refined reciprocal (validated R6/R8).
__device__ __forceinline__ float refined_rcp(float d) {
  float rd = __builtin_amdgcn_rcpf(d);
  return fmaf(fmaf(-d, rd, 1.0f), rd, rd);
}
__device__ __forceinline__ float fdiv_m(float v, float d, float rd) {
  float q0 = v * rd;
  float r = fmaf(-d, q0, v);
  return fmaf(r, rd, q0);
}

__device__ __forceinline__ void block_atomic_maxf(float v, unsigned* slot) {
  for (int off = 32; off > 0; off >>= 1) v = fmaxf(v, __shfl_xor(v, off, 64));
  __shared__ float red4[4];
  int lane = threadIdx.x & 63, w = threadIdx.x >> 6;
  if (lane == 0) red4[w] = v;
  __syncthreads();
  if (threadIdx.x == 0)
    atomicMax(slot, __float_as_uint(fmaxf(fmaxf(red4[0], red4[1]), fmaxf(red4[2], red4[3]))));
}

__device__ __forceinline__ int qpack4(float a0, float a1, float a2, float a3, float s) {
  int i0 = (int)fminf(fmaxf(rintf(a0 / s), -QMAXF), QMAXF);
  int i1 = (int)fminf(fmaxf(rintf(a1 / s), -QMAXF), QMAXF);
  int i2 = (int)fminf(fmaxf(rintf(a2 / s), -QMAXF), QMAXF);
  int i3 = (int)fminf(fmaxf(rintf(a3 / s), -QMAXF), QMAXF);
  return (i0 & 255) | ((i1 & 255) << 8) | ((i2 & 255) << 16) | ((i3 & 255) << 24);
}

__device__ __forceinline__ float fabs4max(float4 v) {
  return fmaxf(fmaxf(fabsf(v.x), fabsf(v.y)), fmaxf(fabsf(v.z), fabsf(v.w)));
}

// ---------------- fused maxabs: X + 4 weights + 4 biases ----------------

__global__ __launch_bounds__(256) void maxabs_all(const float4* __restrict__ X,
                                                  const float4* __restrict__ w0, const float4* __restrict__ w1,
                                                  const float4* __restrict__ w2, const float4* __restrict__ w3,
                                                  const float* __restrict__ b0, const float* __restrict__ b1,
                                                  const float* __restrict__ b2, const float* __restrict__ b3,
                                                  unsigned* __restrict__ scal) {
  int blk = blockIdx.x, t = threadIdx.x;
  float m = 0.0f;
  unsigned* slot;
  if (blk < 1024) {
    int i = blk * 256 + t;
#pragma unroll
    for (int k = 0; k < 3; ++k) m = fmaxf(m, fabs4max(X[i + k * 262144]));
    slot = scal + S_X;
  } else if (blk < 1600) {
    int which = (blk - 1024) / 144, j = (blk - 1024) % 144;
    const float4* p = which == 0 ? w0 : which == 1 ? w1 : which == 2 ? w2 : w3;
    int i = j * 256 + t;
#pragma unroll
    for (int k = 0; k < 4; ++k) m = fmaxf(m, fabs4max(p[i + k * 36864]));
    slot = scal + S_WQ + which;
  } else {
    int which = blk - 1600;
    const float* p = which == 0 ? b0 : which == 1 ? b1 : which == 2 ? b2 : b3;
    for (int i = t; i < 768; i += 256) m = fmaxf(m, fabsf(p[i]));
    slot = scal + S_BQ + which;
  }
  block_atomic_maxf(m, slot);
}

// ---------------- fused quant: X + 4 weights + qbias(q,k,v) ----------------

__device__ __forceinline__ void qbias_body(const float* __restrict__ b, float* __restrict__ qb,
                                           const unsigned* __restrict__ scal, int slotX, int slotW, int slotB, int j) {
  if (j >= 768) return;
  float in_scale = __uint_as_float(scal[slotX]) / QMAXF;   // no clamp (reference)
  float w_scale  = __uint_as_float(scal[slotW]) / QMAXF;
  float bias_scale = in_scale * w_scale;
  float tmax = __uint_as_float(scal[slotB]) / bias_scale;
  float st = fmaxf(tmax / QMAXF, 1e-8f);
  float t = b[j] / bias_scale;
  float qv = fminf(fmaxf(rintf(t / st), -127.0f), 127.0f) * st;
  qb[j] = qv * bias_scale;
}

__global__ __launch_bounds__(256) void quant_all(const float4* __restrict__ X, int* __restrict__ qX,
                                                 const float4* __restrict__ w0, const float4* __restrict__ w1,
                                                 const float4* __restrict__ w2, const float4* __restrict__ w3,
                                                 int* __restrict__ o0, int* __restrict__ o1,
                                                 int* __restrict__ o2, int* __restrict__ o3,
                                                 const float* __restrict__ bq, const float* __restrict__ bk,
                                                 const float* __restrict__ bv,
                                                 float* __restrict__ qbq, float* __restrict__ qbk,
                                                 float* __restrict__ qbv,
                                                 const unsigned* __restrict__ scal) {
  int blk = blockIdx.x, t = threadIdx.x;
  if (blk < 1024) {
    float s = qscale(scal, S_X);
    int i = blk * 256 + t;
#pragma unroll
    for (int k = 0; k < 3; ++k) {
      float4 v = X[i + k * 262144];
      qX[i + k * 262144] = qpack4(v.x, v.y, v.z, v.w, s);
    }
  } else if (blk < 1600) {
    int which = (blk - 1024) / 144, j = (blk - 1024) % 144;
    const float4* p = which == 0 ? w0 : which == 1 ? w1 : which == 2 ? w2 : w3;
    int* o = which == 0 ? o0 : which == 1 ? o1 : which == 2 ? o2 : o3;
    float s = qscale(scal, S_WQ + which);
    int i = j * 256 + t;
#pragma unroll
    for (int k = 0; k < 4; ++k) {
      float4 v = p[i + k * 36864];
      o[i + k * 36864] = qpack4(v.x, v.y, v.z, v.w, s);
    }
  } else {
    int proj = (blk - 1600) / 3, part = (blk - 1600) % 3;
    int j = part * 256 + t;
    const float* b = proj == 0 ? bq : proj == 1 ? bk : bv;
    float* qb = proj == 0 ? qbq : proj == 1 ? qbk : qbv;
    qbias_body(b, qb, scal, S_X, S_WQ + proj, S_BQ + proj, j);
  }
}

// ---------------- LDS-staged MFMA int8 GEMM (proven R5/R6 structure) ----------------

__device__ __forceinline__ void gemm_body(const int8_t* __restrict__ A, const int8_t* __restrict__ Bm,
                                          float* __restrict__ C, const float* __restrict__ bias,
                                          unsigned* __restrict__ scal, int slotA, int slotB, int maxslot) {
  __shared__ int8_t Al[16384];
  __shared__ int8_t Bl[8192];
  int t = threadIdx.x, lane = t & 63, w = t >> 6, l15 = lane & 15, kg4 = lane >> 4;
  int bm = blockIdx.y * 128, bn = blockIdx.x * 64;
  float sAB = qscale(scal, slotA) * qscale(scal, slotB);
  int srow = t >> 3, scol = (t & 7) * 16;
  int ssw = scol ^ ((srow & 7) << 4);
  i32x4 acc[2][4];
#pragma unroll
  for (int rt = 0; rt < 2; ++rt)
#pragma unroll
    for (int ct = 0; ct < 4; ++ct)
#pragma unroll
      for (int r = 0; r < 4; ++r) acc[rt][ct][r] = 0;

  for (int kt = 0; kt < 6; ++kt) {
    int kc = kt * 128;
#pragma unroll
    for (int j = 0; j < 4; ++j) {
      int r = j * 32 + srow;
      GLOAD_LDS16(A + (size_t)(bm + r) * 768 + kc + ssw, Al + r * 128 + scol);
    }
#pragma unroll
    for (int j = 0; j < 2; ++j) {
      int r = j * 32 + srow;
      GLOAD_LDS16(Bm + (size_t)(bn + r) * 768 + kc + ssw, Bl + r * 128 + scol);
    }
    __syncthreads();
#pragma unroll
    for (int kg = 0; kg < 2; ++kg) {
      int kcol = kg * 64 + kg4 * 16;
      i32x4 af[2], bf[4];
#pragma unroll
      for (int rt = 0; rt < 2; ++rt) {
        int ar = w * 32 + rt * 16 + l15;
        af[rt] = *(const i32x4*)(Al + ar * 128 + (kcol ^ ((ar & 7) << 4)));
      }
#pragma unroll
      for (int ct = 0; ct < 4; ++ct) {
        int br = ct * 16 + l15;
        bf[ct] = *(const i32x4*)(Bl + br * 128 + (kcol ^ ((br & 7) << 4)));
      }
#pragma unroll
      for (int rt = 0; rt < 2; ++rt)
#pragma unroll
        for (int ct = 0; ct < 4; ++ct)
          acc[rt][ct] = __builtin_amdgcn_mfma_i32_16x16x64_i8(af[rt], bf[ct], acc[rt][ct], 0, 0, 0);
    }
    __syncthreads();
  }
  float am = 0.0f;
#pragma unroll
  for (int rt = 0; rt < 2; ++rt)
#pragma unroll
    for (int ct = 0; ct < 4; ++ct) {
      int col = bn + ct * 16 + l15;
      float bv = bias[col];
#pragma unroll
      for (int r = 0; r < 4; ++r) {
        int row = bm + w * 32 + rt * 16 + kg4 * 4 + r;
        float v = (float)acc[rt][ct][r] * sAB;
        float yv = v + bv;
        C[(size_t)row * 768 + col] = yv;
        am = fmaxf(am, fabsf(yv));
      }
    }
  if (maxslot >= 0) block_atomic_maxf(am, scal + maxslot);
}

__global__ __launch_bounds__(256) void gemm_qkv(const int8_t* __restrict__ qX,
                                                const int8_t* __restrict__ qWq, const int8_t* __restrict__ qWk,
                                                const int8_t* __restrict__ qWv,
                                                const float* __restrict__ qbq, const float* __restrict__ qbk,
                                                const float* __restrict__ qbv,
                                                float* __restrict__ Yq, float* __restrict__ Yk, float* __restrict__ Yv,
                                                unsigned* __restrict__ scal) {
  int z = blockIdx.z;
  const int8_t* Bm = z == 0 ? qWq : z == 1 ? qWk : qWv;
  const float* bias = z == 0 ? qbq : z == 1 ? qbk : qbv;
  float* C = z == 0 ? Yq : z == 1 ? Yk : Yv;
  gemm_body(qX, Bm, C, bias, scal, S_X, S_WQ + z, S_YQ + z);
}

__global__ __launch_bounds__(256) void gemm_proj(const int8_t* __restrict__ A, const int8_t* __restrict__ Bm,
                                                 float* __restrict__ C, const float* __restrict__ bias,
                                                 unsigned* __restrict__ scal, int slotA, int slotB, int maxslot) {
  gemm_body(A, Bm, C, bias, scal, slotA, slotB, maxslot);
}

// ---------------- head re-layout + quant ----------------

__device__ __forceinline__ void qheads_qk_body(const float* __restrict__ Y, int* __restrict__ q,
                                               const unsigned* __restrict__ scal, int slot, int i) {
  float s = qscale(scal, slot);
  int d0 = (i & 15) * 4;
  int sI = (i >> 4) & 511;
  int bh = i >> 13;
  int h = bh % 12, b = bh / 12;
  const float* src = Y + ((size_t)(b * 512 + sI)) * 768 + h * 64 + d0;
  float4 v = *(const float4*)src;
  q[i] = qpack4(v.x, v.y, v.z, v.w, s);
}

__device__ __forceinline__ void qheads_v_body(const float* __restrict__ Y, int8_t* __restrict__ q,
                                              const unsigned* __restrict__ scal, int blkv) {
  __shared__ int8_t T[64][68];
  int bh = blkv >> 3, sb = blkv & 7;
  int b = bh / 12, h = bh % 12;
  float s = qscale(scal, S_YV);
  int d = threadIdx.x & 63, sl = threadIdx.x >> 6;
#pragma unroll
  for (int i = 0; i < 16; ++i) {
    int s_local = i * 4 + sl;
    float y = Y[((size_t)(b * 512 + sb * 64 + s_local)) * 768 + h * 64 + d];
    float tq = fminf(fmaxf(rintf(y / s), -QMAXF), QMAXF);
    T[d][s_local] = (int8_t)tq;
  }
  __syncthreads();
  int s4 = (threadIdx.x & 15) * 4, dl = threadIdx.x >> 4;
#pragma unroll
  for (int i = 0; i < 4; ++i) {
    int d_ = i * 16 + dl;
    int packed = (T[d_][s4] & 255) | ((T[d_][s4 + 1] & 255) << 8) |
                 ((T[d_][s4 + 2] & 255) << 16) | ((T[d_][s4 + 3] & 255) << 24);
    *(int*)(q + (size_t)bh * 32768 + (size_t)d_ * 512 + sb * 64 + s4) = packed;
  }
}

__global__ __launch_bounds__(256) void quant_heads_all(const float* __restrict__ Yq, int* __restrict__ qq,
                                                       const float* __restrict__ Yk, int* __restrict__ qk,
                                                       const float* __restrict__ Yv, int8_t* __restrict__ qvT,
                                                       const unsigned* __restrict__ scal) {
  int blk = blockIdx.x;
  if (blk < 3072)      qheads_qk_body(Yq, qq, scal, S_YQ, blk * 256 + threadIdx.x);
  else if (blk < 6144) qheads_qk_body(Yk, qk, scal, S_YK, (blk - 3072) * 256 + threadIdx.x);
  else                 qheads_v_body(Yv, qvT, scal, blk - 6144);
}

__global__ __launch_bounds__(256) void quant_heads_qk(const float* __restrict__ Y, int* __restrict__ q,
                                                      const unsigned* __restrict__ scal, int slot) {
  qheads_qk_body(Y, q, scal, slot, blockIdx.x * 256 + threadIdx.x);
}
__global__ __launch_bounds__(256) void quant_heads_v(const float* __restrict__ Y, int8_t* __restrict__ q,
                                                     const unsigned* __restrict__ scal) {
  qheads_v_body(Y, q, scal, blockIdx.x);
}

// ---------------- attention e-phase (R6/R10-proven 4-wave version, fallback pass2) ----------------

__device__ __forceinline__ void attn_e_phase(const int8_t* __restrict__ qbase,
                                             const int8_t* __restrict__ kbase,
                                             int rb, float pref, const PLA& pla,
                                             float (&v)[8][4], float (*red)[16], float& denom) {
  __shared__ float2 ae2[11];   // (a[i], a[i+1])
  __shared__ float2 mcs[11];   // (m[i], c[i])
  int t = threadIdx.x, lane = t & 63, w = t >> 6, l15 = lane & 15, kg = lane >> 4;
  if (t < 11) {
    ae2[t] = make_float2(pla.a[t], pla.a[t + 1]);
    mcs[t] = make_float2(pla.m[t], pla.c[t]);
  }
  i32x4 zero = {0, 0, 0, 0};
  i32x4 qf = *(const i32x4*)(qbase + (size_t)(rb * 16 + l15) * 64 + kg * 16);
  i32x4 acc[8];
#pragma unroll
  for (int i = 0; i < 8; ++i) {
    i32x4 kf = *(const i32x4*)(kbase + (size_t)((w * 8 + i) * 16 + l15) * 64 + kg * 16);
    acc[i] = __builtin_amdgcn_mfma_i32_16x16x64_i8(kf, qf, zero, 0, 0, 0);
  }
  float mx = -3.4e38f;
#pragma unroll
  for (int i = 0; i < 8; ++i)
#pragma unroll
    for (int r = 0; r < 4; ++r) {
      v[i][r] = (float)acc[i][r] * pref;
      mx = fmaxf(mx, v[i][r]);
    }
  mx = fmaxf(mx, __shfl_xor(mx, 16, 64));
  mx = fmaxf(mx, __shfl_xor(mx, 32, 64));
  if (lane < 16) red[w][l15] = mx;
  __syncthreads();                     // also covers ae2/mcs init
  float gm = fmaxf(fmaxf(red[0][l15], red[1][l15]), fmaxf(red[2][l15], red[3][l15]));
  __syncthreads();
  float s = 0.0f;
#pragma unroll
  for (int i = 0; i < 8; ++i)
#pragma unroll
    for (int r = 0; r < 4; ++r) {
      float x = v[i][r] - gm;
      float sh = rintf(x * 67108864.0f);
      sh = fmaxf(sh, -671088640.0f);
      sh = fminf(sh, 0.0f);
      float xc = sh * (1.0f / 67108864.0f);
      float tf = (xc + 10.0f) * 1.2f;
      int i0 = (int)tf;
      i0 = i0 > 10 ? 10 : i0;
      float2 ee = ae2[i0];
      int idx = i0 + ((i0 < 10 && xc >= ee.y) ? 1 : 0) - ((xc < ee.x) ? 1 : 0);
      float2 mc = mcs[idx];
      float e = mc.x * xc;   // no fma: contract off
      e = e + mc.y;
      v[i][r] = e;
      s += e;
    }
  s += __shfl_xor(s, 16, 64);
  s += __shfl_xor(s, 32, 64);
  if (lane < 16) red[w][l15] = s;
  __syncthreads();
  denom = (((red[0][l15] + red[1][l15]) + red[2][l15]) + red[3][l15]) + 1e-9f;
  __syncthreads();   // protect red reuse by subsequent calls
}

// ---------------- pass1: 2 units/block, split reduce arrays (2 barriers/unit) ----------------
// Consecutive units share bh -> K-tile + PLA tables loaded once, reused. Arithmetic is
// instruction-identical to attn_e_phase (same per-lane order, same shfl/reduce order) so
// fallback pass2's denom matches bit-exactly. q15 contract unchanged: unit*4096, thread-major
// dwordx4, nontemporal. Barrier-safety: redm written after prior barrier B (all waves past
// their gm reads); reds written after barrier A (all waves past their denom reads).

__global__ __launch_bounds__(256) void attn_pass1(const int8_t* __restrict__ qq,
                                                  const int8_t* __restrict__ qk,
                                                  int* __restrict__ q15w,
                                                  unsigned* __restrict__ scal, PLA pla) {
  __shared__ float2 ae2[11];
  __shared__ float2 mcs[11];
  __shared__ float redm[4][16];
  __shared__ float reds[4][16];
  int t = threadIdx.x, lane = t & 63, w = t >> 6, l15 = lane & 15, kg = lane >> 4;
  if (t < 11) {
    ae2[t] = make_float2(pla.a[t], pla.a[t + 1]);
    mcs[t] = make_float2(pla.m[t], pla.c[t]);
  }
  float pref = (qscale(scal, S_YQ) * qscale(scal, S_YK)) * 0.125f;
  float dmLocal = 3.4e38f;
  i32x4 zero = {0, 0, 0, 0};
#pragma unroll
  for (int k = 0; k < 2; ++k) {
    int unit = blockIdx.x * 2 + k, rb = unit & 31, bh = unit >> 5;
    const int8_t* qbase = qq + (size_t)bh * 32768;
    const int8_t* kbase = qk + (size_t)bh * 32768;
    i32x4 qf = *(const i32x4*)(qbase + (size_t)(rb * 16 + l15) * 64 + kg * 16);
    i32x4 acc[8];
#pragma unroll
    for (int i = 0; i < 8; ++i) {
      i32x4 kf = *(const i32x4*)(kbase + (size_t)((w * 8 + i) * 16 + l15) * 64 + kg * 16);
      acc[i] = __builtin_amdgcn_mfma_i32_16x16x64_i8(kf, qf, zero, 0, 0, 0);
    }
    float v[8][4];
    float mx = -3.4e38f;
#pragma unroll
    for (int i = 0; i < 8; ++i)
#pragma unroll
      for (int r = 0; r < 4; ++r) {
        v[i][r] = (float)acc[i][r] * pref;
        mx = fmaxf(mx, v[i][r]);
      }
    mx = fmaxf(mx, __shfl_xor(mx, 16, 64));
    mx = fmaxf(mx, __shfl_xor(mx, 32, 64));
    if (lane < 16) redm[w][l15] = mx;
    __syncthreads();                   // barrier A (covers table init at k=0; reds(u-1) reads done)
    float gm = fmaxf(fmaxf(redm[0][l15], redm[1][l15]), fmaxf(redm[2][l15], redm[3][l15]));
    float s = 0.0f;
#pragma unroll
    for (int i = 0; i < 8; ++i)
#pragma unroll
      for (int r = 0; r < 4; ++r) {
        float x = v[i][r] - gm;
        float sh = rintf(x * 67108864.0f);
        sh = fmaxf(sh, -671088640.0f);
        sh = fminf(sh, 0.0f);
        float xc = sh * (1.0f / 67108864.0f);
        float tf = (xc + 10.0f) * 1.2f;
        int i0 = (int)tf;
        i0 = i0 > 10 ? 10 : i0;
        float2 ee = ae2[i0];
        int idx = i0 + ((i0 < 10 && xc >= ee.y) ? 1 : 0) - ((xc < ee.x) ? 1 : 0);
        float2 mc = mcs[idx];
        float e = mc.x * xc;   // no fma: contract off
        e = e + mc.y;
        v[i][r] = e;
        s += e;
      }
    s += __shfl_xor(s, 16, 64);
    s += __shfl_xor(s, 32, 64);
    if (lane < 16) reds[w][l15] = s;
    __syncthreads();                   // barrier B (redm(u) reads done; reds(u) ready)
    float denom = (((reds[0][l15] + reds[1][l15]) + reds[2][l15]) + reds[3][l15]) + 1e-9f;
    dmLocal = fminf(dmLocal, denom);
    if (q15w) {
      float rdn = refined_rcp(denom);
      int d[16];
#pragma unroll
      for (int i = 0; i < 8; ++i) {
        int q15i[4];
#pragma unroll
        for (int r = 0; r < 4; ++r) {
          float sm32 = fdiv_m(v[i][r] * 32768.0f, denom, rdn);
          q15i[r] = (int)fminf(fmaxf(rintf(sm32), -32768.0f), 32767.0f);
        }
        d[i * 2]     = (q15i[0] & 0xffff) | (q15i[1] << 16);
        d[i * 2 + 1] = (q15i[2] & 0xffff) | (q15i[3] << 16);
      }
      i32x4* q15v = (i32x4*)(q15w + (size_t)unit * 4096);
#pragma unroll
      for (int j = 0; j < 4; ++j) {
        i32x4 pk = { d[4 * j], d[4 * j + 1], d[4 * j + 2], d[4 * j + 3] };
        __builtin_nontemporal_store(pk, &q15v[j * 256 + t]);
      }
    }
  }
  float dm = dmLocal;
  dm = fminf(dm, __shfl_xor(dm, 1, 64));
  dm = fminf(dm, __shfl_xor(dm, 2, 64));
  dm = fminf(dm, __shfl_xor(dm, 4, 64));
  dm = fminf(dm, __shfl_xor(dm, 8, 64));
  dm = fminf(dm, __shfl_xor(dm, 16, 64));
  dm = fminf(dm, __shfl_xor(dm, 32, 64));
  if (lane == 0 && w == 0) atomicMax(scal + S_DMIN, 0x7f800000u - __float_as_uint(dm));
  else if (lane == 0) {
    // other waves contribute too (their dmLocal may differ is false -- all threads saw same
    // denoms; single atomic from wave 0 suffices)
  }
}

__device__ __forceinline__ float derive_sp(const unsigned* scal, const PLA& pla) {
  float dmin = __uint_as_float(0x7f800000u - scal[S_DMIN]);
  float smm = pla.c[10] / dmin;
  float q15m = fminf(fmaxf(rintf(smm * 32768.0f), -32768.0f), 32767.0f);
  return fmaxf((q15m * (1.0f / 32768.0f)) / QMAXF, 1e-8f);
}

__device__ __forceinline__ void attn_pv_tail(const int8_t* __restrict__ vT, int8_t (*Ps)[528],
                                             unsigned* __restrict__ scal, float* __restrict__ ctx,
                                             int rb, int bh, float sp) {
  int t = threadIdx.x, lane = t & 63, w = t >> 6, l15 = lane & 15, kg = lane >> 4;
  int b = bh / 12, h = bh % 12;
  float sv = qscale(scal, S_YV);
  i32x4 pacc = {0, 0, 0, 0};
  const int8_t* vbase = vT + (size_t)bh * 32768 + (size_t)(w * 16 + l15) * 512;
#pragma unroll
  for (int ks = 0; ks < 8; ++ks) {
    i32x4 pf = *(const i32x4*)&Ps[l15][ks * 64 + kg * 16];
    i32x4 vf = *(const i32x4*)(vbase + ks * 64 + kg * 16);
    pacc = __builtin_amdgcn_mfma_i32_16x16x64_i8(pf, vf, pacc, 0, 0, 0);
  }
  float spv = sp * sv;
  float am = 0.0f;
#pragma unroll
  for (int r = 0; r < 4; ++r) {
    int srow = rb * 16 + kg * 4 + r;
    float val = (float)pacc[r] * spv;
    ctx[((size_t)(b * 512 + srow)) * 768 + h * 64 + w * 16 + l15] = val;
    am = fmaxf(am, fabsf(val));
  }
  block_atomic_maxf(am, scal + S_CTX);
}

__global__ __launch_bounds__(256) void attn_pass2_load(const int* __restrict__ q15r,
                                                       const int8_t* __restrict__ vT,
                                                       unsigned* __restrict__ scal,
                                                       float* __restrict__ ctx, PLA pla) {
  __shared__ alignas(16) int8_t Ps[16][528];
  int rb = blockIdx.x & 31, bh = blockIdx.x >> 5;
  float sp = derive_sp(scal, pla);
  float rsp = refined_rcp(sp);
  int t = threadIdx.x, lane = t & 63, w = t >> 6, l15 = lane & 15, kg = lane >> 4;
  const i32x4* q15v = (const i32x4*)(q15r + (size_t)blockIdx.x * 4096);
  int d[16];
#pragma unroll
  for (int j = 0; j < 4; ++j) {
    i32x4 pk = __builtin_nontemporal_load(&q15v[j * 256 + t]);
    d[4 * j] = pk[0]; d[4 * j + 1] = pk[1]; d[4 * j + 2] = pk[2]; d[4 * j + 3] = pk[3];
  }
#pragma unroll
  for (int i = 0; i < 8; ++i) {
    int u01 = d[i * 2], u23 = d[i * 2 + 1];
    int q15i[4] = { (int)(short)(u01 & 0xffff), u01 >> 16,
                    (int)(short)(u23 & 0xffff), u23 >> 16 };
    uint32_t packed = 0;
#pragma unroll
    for (int r = 0; r < 4; ++r) {
      float pv = (float)q15i[r] * (1.0f / 32768.0f);
      int qp = (int)fminf(fmaxf(rintf(fdiv_m(pv, sp, rsp)), -QMAXF), QMAXF);
      packed |= (uint32_t)(qp & 255) << (8 * r);
    }
    *(uint32_t*)&Ps[l15][(w * 8 + i) * 16 + kg * 4] = packed;
  }
  __syncthreads();
  attn_pv_tail(vT, Ps, scal, ctx, rb, bh, sp);
}

// fallback pass2: recompute e-phase, quantize, PV (R6 path)
__global__ __launch_bounds__(256) void attn_pass2_recompute(const int8_t* __restrict__ qq,
                                                            const int8_t* __restrict__ qk,
                                                            const int8_t* __restrict__ vT,
                                                            unsigned* __restrict__ scal,
                                                            float* __restrict__ ctx, PLA pla) {
  __shared__ float red[4][16];
  __shared__ alignas(16) int8_t Ps[16][528];
  int rb = blockIdx.x & 31, bh = blockIdx.x >> 5;
  float pref = (qscale(scal, S_YQ) * qscale(scal, S_YK)) * 0.125f;
  float sp = derive_sp(scal, pla);
  float rsp = refined_rcp(sp);
  float v[8][4];
  float denom;
  attn_e_phase(qq + (size_t)bh * 32768, qk + (size_t)bh * 32768, rb, pref, pla, v, red, denom);
  float rdn = refined_rcp(denom);
  int t = threadIdx.x, lane = t & 63, w = t >> 6, l15 = lane & 15, kg = lane >> 4;
#pragma unroll
  for (int i = 0; i < 8; ++i) {
    uint32_t packed = 0;
#pragma unroll
    for (int r = 0; r < 4; ++r) {
      float sm32 = fdiv_m(v[i][r] * 32768.0f, denom, rdn);
      float q15 = fminf(fmaxf(rintf(sm32), -32768.0f), 32767.0f);
      float pv = q15 * (1.0f / 32768.0f);
      int qp = (int)fminf(fmaxf(rintf(fdiv_m(pv, sp, rsp)), -QMAXF), QMAXF);
      packed |= (uint32_t)(qp & 255) << (8 * r);
    }
    *(uint32_t*)&Ps[l15][(w * 8 + i) * 16 + kg * 4] = packed;
  }
  __syncthreads();
  attn_pv_tail(vT, Ps, scal, ctx, rb, bh, sp);
}

// ---------------- collapsed ctx double-quant + qbias_o (R9-proven) ----------------
// q2 == q0 identity (R8-proven): with ctxq1max = fl(127*s1), s2 = s1*(1 +- 1ulp), so
// rint(q0*s1/s2) == q0 for |q0|<=127. qctx2 = q0 directly; S_CTXQ1 <- fl(127*s1).

__global__ __launch_bounds__(256) void ctx_q12_plus(const float4* __restrict__ ctx, int* __restrict__ q2o,
                                                    const float* __restrict__ bo, float* __restrict__ qbo,
                                                    unsigned* __restrict__ scal) {
  int blk = blockIdx.x;
  float s1 = qscale(scal, S_CTX);
  float ctxq1max = 127.0f * s1;
  if (blk < 3072) {
    float rs1 = refined_rcp(s1);
    int i = blk * 256 + threadIdx.x;
    float4 c = ctx[i];
    int q0 = (int)fminf(fmaxf(rintf(fdiv_m(c.x, s1, rs1)), -QMAXF), QMAXF);
    int q1 = (int)fminf(fmaxf(rintf(fdiv_m(c.y, s1, rs1)), -QMAXF), QMAXF);
    int q2 = (int)fminf(fmaxf(rintf(fdiv_m(c.z, s1, rs1)), -QMAXF), QMAXF);
    int q3 = (int)fminf(fmaxf(rintf(fdiv_m(c.w, s1, rs1)), -QMAXF), QMAXF);
    q2o[i] = (q0 & 255) | ((q1 & 255) << 8) | ((q2 & 255) << 16) | ((q3 & 255) << 24);
  } else {
    if (blk == 3072 && threadIdx.x == 0) scal[S_CTXQ1] = __float_as_uint(ctxq1max);
    int j = (blk - 3072) * 256 + threadIdx.x;
    if (j < 768) {
      float in_scale = ctxq1max / QMAXF;   // no clamp (reference)
      float w_scale = __uint_as_float(scal[S_WO]) / QMAXF;
      float bias_scale = in_scale * w_scale;
      float tmax = __uint_as_float(scal[S_BO]) / bias_scale;
      float st = fmaxf(tmax / QMAXF, 1e-8f);
      float tv = bo[j] / bias_scale;
      float qv = fminf(fmaxf(rintf(tv / st), -127.0f), 127.0f) * st;
      qbo[j] = qv * bias_scale;
    }
  }
}

// ---------------- host: PLA build (replicates np.polyfit degree-1 LS in f64) ----------------

static void build_pla(PLA& p) {
  double xs[1001], ys[1001];
  double step = 10.0 / 1000.0;
  for (int j = 0; j <= 1000; ++j) xs[j] = (double)j * step + (-10.0);
  xs[1000] = 0.0;
  for (int j = 0; j <= 1000; ++j) ys[j] = exp(xs[j]);
  double estep = 10.0 / 12.0;
  for (int i = 0; i < 12; ++i) {
    double a = (double)i * estep + (-10.0);
    double bb = (i + 1 == 12) ? 0.0 : (double)(i + 1) * estep + (-10.0);
    double n = 0, Sx = 0, Sy = 0, Sxx = 0, Sxy = 0;
    for (int j = 0; j <= 1000; ++j) {
      if (xs[j] >= a && xs[j] <= bb) {
        double x = xs[j], y = ys[j];
        n += 1.0; Sx += x; Sy += y; Sxx += x * x; Sxy += x * y;
      }
    }
    double det = n * Sxx - Sx * Sx;
    p.m[i] = (float)((n * Sxy - Sx * Sy) / det);
    p.c[i] = (float)((Sxx * Sy - Sx * Sxy) / det);
    p.a[i] = (float)a;
  }
}

// ---------------- launch ----------------

extern "C" void kernel_launch(void* const* d_in, const int* in_sizes, int n_in,
                              void* d_out, int out_size, void* d_ws, size_t ws_size,
                              hipStream_t stream) {
  const float* X  = (const float*)d_in[0];
  const float* Wq = (const float*)d_in[1];
  const float* bq = (const float*)d_in[2];
  const float* Wk = (const float*)d_in[3];
  const float* bk = (const float*)d_in[4];
  const float* Wv = (const float*)d_in[5];
  const float* bv = (const float*)d_in[6];
  const float* Wo = (const float*)d_in[7];
  const float* bo = (const float*)d_in[8];
  float* out = (float*)d_out;
  (void)n_in; (void)in_sizes; (void)out_size;

  PLA pla;
  build_pla(pla);

  const size_t NX = 8 * 512 * 768;   // 3145728
  const size_t NW = 768 * 768;       // 589824
  const size_t Q15_BYTES = 3072ull * 16384;  // 48 MiB

  uint8_t* ws = (uint8_t*)d_ws;
  size_t off = 0;
  auto alloc = [&](size_t bytes) -> void* {
    void* p = ws + off;
    off += (bytes + 255) & ~(size_t)255;
    return p;
  };

  unsigned* scal = (unsigned*)alloc(256);
  int8_t* qWq = (int8_t*)alloc(NW);
  int8_t* qWk = (int8_t*)alloc(NW);
  int8_t* qWv = (int8_t*)alloc(NW);
  int8_t* qWo = (int8_t*)alloc(NW);
  float* qbq = (float*)alloc(768 * 4);
  float* qbk = (float*)alloc(768 * 4);
  float* qbv = (float*)alloc(768 * 4);
  float* qbo = (float*)alloc(768 * 4);
  int8_t* qX = (int8_t*)alloc(NX);       // reused as qctx2
  int8_t* qctx2 = qX;

  size_t fixed = off;
  size_t need_fast = fixed + Q15_BYTES + (4 * NX) + NX + 512;
  bool fast = ws_size >= need_fast;

  hipMemsetAsync(scal, 0, 256, stream);

  if (fast) {
    uint8_t* D = (uint8_t*)alloc(Q15_BYTES);        // Yq|Yk|Yv then q15
    float* Yq = (float*)D;
    float* Yk = (float*)(D + NX * 4);
    float* Yv = (float*)(D + 2 * NX * 4);
    int* q15buf = (int*)D;
    uint8_t* E = (uint8_t*)alloc(4 * NX);           // qq|qk then ctx
    int8_t* qq = (int8_t*)E;
    int8_t* qk = (int8_t*)(E + NX);
    float* ctx = (float*)E;
    int8_t* qvT = (int8_t*)alloc(NX);

    maxabs_all<<<1604, 256, 0, stream>>>((const float4*)X, (const float4*)Wq, (const float4*)Wk,
                                         (const float4*)Wv, (const float4*)Wo, bq, bk, bv, bo, scal);
    quant_all<<<1609, 256, 0, stream>>>((const float4*)X, (int*)qX,
                                        (const float4*)Wq, (const float4*)Wk, (const float4*)Wv, (const float4*)Wo,
                                        (int*)qWq, (int*)qWk, (int*)qWv, (int*)qWo,
                                        bq, bk, bv, qbq, qbk, qbv, scal);
    gemm_qkv<<<dim3(12, 32, 3), 256, 0, stream>>>(qX, qWq, qWk, qWv, qbq, qbk, qbv, Yq, Yk, Yv, scal);
    quant_heads_all<<<6912, 256, 0, stream>>>(Yq, (int*)qq, Yk, (int*)qk, Yv, qvT, scal);
    attn_pass1<<<1536, 256, 0, stream>>>(qq, qk, q15buf, scal, pla);         // q15 overwrites Y (dead)
    attn_pass2_load<<<3072, 256, 0, stream>>>(q15buf, qvT, scal, ctx, pla);  // ctx overwrites qq/qk (dead)
    ctx_q12_plus<<<3075, 256, 0, stream>>>((const float4*)ctx, (int*)qctx2, bo, qbo, scal);
    gemm_proj<<<dim3(12, 32), 256, 0, stream>>>(qctx2, qWo, out, qbo, scal, S_CTXQ1, S_WO, -1);
  } else {
    float* Y = (float*)alloc(NX * 4);               // then ctx
    float* ctx = Y;
    int8_t* qq = (int8_t*)alloc(NX);
    int8_t* qk = (int8_t*)alloc(NX);
    int8_t* qvT = (int8_t*)alloc(NX);

    maxabs_all<<<1604, 256, 0, stream>>>((const float4*)X, (const float4*)Wq, (const float4*)Wk,
                                         (const float4*)Wv, (const float4*)Wo, bq, bk, bv, bo, scal);
    quant_all<<<1609, 256, 0, stream>>>((const float4*)X, (int*)qX,
                                        (const float4*)Wq, (const float4*)Wk, (const float4*)Wv, (const float4*)Wo,
                                        (int*)qWq, (int*)qWk, (int*)qWv, (int*)qWo,
                                        bq, bk, bv, qbq, qbk, qbv, scal);
    gemm_proj<<<dim3(12, 32), 256, 0, stream>>>(qX, qWq, Y, qbq, scal, S_X, S_WQ, S_YQ);
    quant_heads_qk<<<3072, 256, 0, stream>>>(Y, (int*)qq, scal, S_YQ);
    gemm_proj<<<dim3(12, 32), 256, 0, stream>>>(qX, qWk, Y, qbk, scal, S_X, S_WK, S_YK);
    quant_heads_qk<<<3072, 256, 0, stream>>>(Y, (int*)qk, scal, S_YK);
    gemm_proj<<<dim3(12, 32), 256, 0, stream>>>(qX, qWv, Y, qbv, scal, S_X, S_WV, S_YV);
    quant_heads_v<<<768, 256, 0, stream>>>(Y, qvT, scal);
    attn_pass1<<<1536, 256, 0, stream>>>(qq, qk, (int*)nullptr, scal, pla);
    attn_pass2_recompute<<<3072, 256, 0, stream>>>(qq, qk, qvT, scal, ctx, pla);
    ctx_q12_plus<<<3075, 256, 0, stream>>>((const float4*)ctx, (int*)qctx2, bo, qbo, scal);
    gemm_proj<<<dim3(12, 32), 256, 0, stream>>>(qctx2, qWo, out, qbo, scal, S_CTXQ1, S_WO, -1);
  }
}

// Round 14
// 150.838 us; speedup vs baseline: 1.1683x; 1.0576x over previous
//
#include <hip/hip_runtime.h>
#include <cstdint>
#include <cmath>
#include <cstddef>

#pragma clang fp contract(off)

#define QMAXF 127.0f

typedef int i32x4 __attribute__((ext_vector_type(4)));

enum {
  S_X = 0, S_WQ, S_WK, S_WV, S_WO, S_BQ, S_BK, S_BV, S_BO,
  S_YQ, S_YK, S_YV, S_CTX, S_CTXQ1, S_DMIN, S_PAD
};

struct PLA { float m[12]; float c[12]; float a[12]; };

#define GLOAD_LDS16(gsrc, ldst) \
  __builtin_amdgcn_global_load_lds((const __attribute__((address_space(1))) void*)(gsrc), \
                                   (__attribute__((address_space(3))) void*)(ldst), 16, 0, 0)

// ---------------- device helpers ----------------

__device__ __forceinline__ float qscale(const unsigned* scal, int slot) {
  // reference: scale = max(maxabs / 127.0, 1e-8)
  return fmaxf(__uint_as_float(scal[slot]) / QMAXF, 1e-8f);
}

// Markstein correctly-rounded division with hoisted refined reciprocal (validated R6/R8).
__device__ __forceinline__ float refined_rcp(float d) {
  float rd = __builtin_amdgcn_rcpf(d);
  return fmaf(fmaf(-d, rd, 1.0f), rd, rd);
}
__device__ __forceinline__ float fdiv_m(float v, float d, float rd) {
  float q0 = v * rd;
  float r = fmaf(-d, q0, v);
  return fmaf(r, rd, q0);
}

__device__ __forceinline__ void block_atomic_maxf(float v, unsigned* slot) {
  for (int off = 32; off > 0; off >>= 1) v = fmaxf(v, __shfl_xor(v, off, 64));
  __shared__ float red4[4];
  int lane = threadIdx.x & 63, w = threadIdx.x >> 6;
  if (lane == 0) red4[w] = v;
  __syncthreads();
  if (threadIdx.x == 0)
    atomicMax(slot, __float_as_uint(fmaxf(fmaxf(red4[0], red4[1]), fmaxf(red4[2], red4[3]))));
}

__device__ __forceinline__ int qpack4(float a0, float a1, float a2, float a3, float s) {
  int i0 = (int)fminf(fmaxf(rintf(a0 / s), -QMAXF), QMAXF);
  int i1 = (int)fminf(fmaxf(rintf(a1 / s), -QMAXF), QMAXF);
  int i2 = (int)fminf(fmaxf(rintf(a2 / s), -QMAXF), QMAXF);
  int i3 = (int)fminf(fmaxf(rintf(a3 / s), -QMAXF), QMAXF);
  return (i0 & 255) | ((i1 & 255) << 8) | ((i2 & 255) << 16) | ((i3 & 255) << 24);
}

__device__ __forceinline__ float fabs4max(float4 v) {
  return fmaxf(fmaxf(fabsf(v.x), fabsf(v.y)), fmaxf(fabsf(v.z), fabsf(v.w)));
}

// ---------------- fused maxabs: X + 4 weights + 4 biases ----------------

__global__ __launch_bounds__(256) void maxabs_all(const float4* __restrict__ X,
                                                  const float4* __restrict__ w0, const float4* __restrict__ w1,
                                                  const float4* __restrict__ w2, const float4* __restrict__ w3,
                                                  const float* __restrict__ b0, const float* __restrict__ b1,
                                                  const float* __restrict__ b2, const float* __restrict__ b3,
                                                  unsigned* __restrict__ scal) {
  int blk = blockIdx.x, t = threadIdx.x;
  float m = 0.0f;
  unsigned* slot;
  if (blk < 1024) {
    int i = blk * 256 + t;
#pragma unroll
    for (int k = 0; k < 3; ++k) m = fmaxf(m, fabs4max(X[i + k * 262144]));
    slot = scal + S_X;
  } else if (blk < 1600) {
    int which = (blk - 1024) / 144, j = (blk - 1024) % 144;
    const float4* p = which == 0 ? w0 : which == 1 ? w1 : which == 2 ? w2 : w3;
    int i = j * 256 + t;
#pragma unroll
    for (int k = 0; k < 4; ++k) m = fmaxf(m, fabs4max(p[i + k * 36864]));
    slot = scal + S_WQ + which;
  } else {
    int which = blk - 1600;
    const float* p = which == 0 ? b0 : which == 1 ? b1 : which == 2 ? b2 : b3;
    for (int i = t; i < 768; i += 256) m = fmaxf(m, fabsf(p[i]));
    slot = scal + S_BQ + which;
  }
  block_atomic_maxf(m, slot);
}

// ---------------- fused quant: X + 4 weights + qbias(q,k,v) ----------------

__device__ __forceinline__ void qbias_body(const float* __restrict__ b, float* __restrict__ qb,
                                           const unsigned* __restrict__ scal, int slotX, int slotW, int slotB, int j) {
  if (j >= 768) return;
  float in_scale = __uint_as_float(scal[slotX]) / QMAXF;   // no clamp (reference)
  float w_scale  = __uint_as_float(scal[slotW]) / QMAXF;
  float bias_scale = in_scale * w_scale;
  float tmax = __uint_as_float(scal[slotB]) / bias_scale;
  float st = fmaxf(tmax / QMAXF, 1e-8f);
  float t = b[j] / bias_scale;
  float qv = fminf(fmaxf(rintf(t / st), -127.0f), 127.0f) * st;
  qb[j] = qv * bias_scale;
}

__global__ __launch_bounds__(256) void quant_all(const float4* __restrict__ X, int* __restrict__ qX,
                                                 const float4* __restrict__ w0, const float4* __restrict__ w1,
                                                 const float4* __restrict__ w2, const float4* __restrict__ w3,
                                                 int* __restrict__ o0, int* __restrict__ o1,
                                                 int* __restrict__ o2, int* __restrict__ o3,
                                                 const float* __restrict__ bq, const float* __restrict__ bk,
                                                 const float* __restrict__ bv,
                                                 float* __restrict__ qbq, float* __restrict__ qbk,
                                                 float* __restrict__ qbv,
                                                 const unsigned* __restrict__ scal) {
  int blk = blockIdx.x, t = threadIdx.x;
  if (blk < 1024) {
    float s = qscale(scal, S_X);
    int i = blk * 256 + t;
#pragma unroll
    for (int k = 0; k < 3; ++k) {
      float4 v = X[i + k * 262144];
      qX[i + k * 262144] = qpack4(v.x, v.y, v.z, v.w, s);
    }
  } else if (blk < 1600) {
    int which = (blk - 1024) / 144, j = (blk - 1024) % 144;
    const float4* p = which == 0 ? w0 : which == 1 ? w1 : which == 2 ? w2 : w3;
    int* o = which == 0 ? o0 : which == 1 ? o1 : which == 2 ? o2 : o3;
    float s = qscale(scal, S_WQ + which);
    int i = j * 256 + t;
#pragma unroll
    for (int k = 0; k < 4; ++k) {
      float4 v = p[i + k * 36864];
      o[i + k * 36864] = qpack4(v.x, v.y, v.z, v.w, s);
    }
  } else {
    int proj = (blk - 1600) / 3, part = (blk - 1600) % 3;
    int j = part * 256 + t;
    const float* b = proj == 0 ? bq : proj == 1 ? bk : bv;
    float* qb = proj == 0 ? qbq : proj == 1 ? qbk : qbv;
    qbias_body(b, qb, scal, S_X, S_WQ + proj, S_BQ + proj, j);
  }
}

// ---------------- LDS-staged MFMA int8 GEMM (proven R5/R6 structure) ----------------

__device__ __forceinline__ void gemm_body(const int8_t* __restrict__ A, const int8_t* __restrict__ Bm,
                                          float* __restrict__ C, const float* __restrict__ bias,
                                          unsigned* __restrict__ scal, int slotA, int slotB, int maxslot) {
  __shared__ int8_t Al[16384];
  __shared__ int8_t Bl[8192];
  int t = threadIdx.x, lane = t & 63, w = t >> 6, l15 = lane & 15, kg4 = lane >> 4;
  int bm = blockIdx.y * 128, bn = blockIdx.x * 64;
  float sAB = qscale(scal, slotA) * qscale(scal, slotB);
  int srow = t >> 3, scol = (t & 7) * 16;
  int ssw = scol ^ ((srow & 7) << 4);
  i32x4 acc[2][4];
#pragma unroll
  for (int rt = 0; rt < 2; ++rt)
#pragma unroll
    for (int ct = 0; ct < 4; ++ct)
#pragma unroll
      for (int r = 0; r < 4; ++r) acc[rt][ct][r] = 0;

  for (int kt = 0; kt < 6; ++kt) {
    int kc = kt * 128;
#pragma unroll
    for (int j = 0; j < 4; ++j) {
      int r = j * 32 + srow;
      GLOAD_LDS16(A + (size_t)(bm + r) * 768 + kc + ssw, Al + r * 128 + scol);
    }
#pragma unroll
    for (int j = 0; j < 2; ++j) {
      int r = j * 32 + srow;
      GLOAD_LDS16(Bm + (size_t)(bn + r) * 768 + kc + ssw, Bl + r * 128 + scol);
    }
    __syncthreads();
#pragma unroll
    for (int kg = 0; kg < 2; ++kg) {
      int kcol = kg * 64 + kg4 * 16;
      i32x4 af[2], bf[4];
#pragma unroll
      for (int rt = 0; rt < 2; ++rt) {
        int ar = w * 32 + rt * 16 + l15;
        af[rt] = *(const i32x4*)(Al + ar * 128 + (kcol ^ ((ar & 7) << 4)));
      }
#pragma unroll
      for (int ct = 0; ct < 4; ++ct) {
        int br = ct * 16 + l15;
        bf[ct] = *(const i32x4*)(Bl + br * 128 + (kcol ^ ((br & 7) << 4)));
      }
#pragma unroll
      for (int rt = 0; rt < 2; ++rt)
#pragma unroll
        for (int ct = 0; ct < 4; ++ct)
          acc[rt][ct] = __builtin_amdgcn_mfma_i32_16x16x64_i8(af[rt], bf[ct], acc[rt][ct], 0, 0, 0);
    }
    __syncthreads();
  }
  float am = 0.0f;
#pragma unroll
  for (int rt = 0; rt < 2; ++rt)
#pragma unroll
    for (int ct = 0; ct < 4; ++ct) {
      int col = bn + ct * 16 + l15;
      float bv = bias[col];
#pragma unroll
      for (int r = 0; r < 4; ++r) {
        int row = bm + w * 32 + rt * 16 + kg4 * 4 + r;
        float v = (float)acc[rt][ct][r] * sAB;
        float yv = v + bv;
        C[(size_t)row * 768 + col] = yv;
        am = fmaxf(am, fabsf(yv));
      }
    }
  if (maxslot >= 0) block_atomic_maxf(am, scal + maxslot);
}

__global__ __launch_bounds__(256) void gemm_qkv(const int8_t* __restrict__ qX,
                                                const int8_t* __restrict__ qWq, const int8_t* __restrict__ qWk,
                                                const int8_t* __restrict__ qWv,
                                                const float* __restrict__ qbq, const float* __restrict__ qbk,
                                                const float* __restrict__ qbv,
                                                float* __restrict__ Yq, float* __restrict__ Yk, float* __restrict__ Yv,
                                                unsigned* __restrict__ scal) {
  int z = blockIdx.z;
  const int8_t* Bm = z == 0 ? qWq : z == 1 ? qWk : qWv;
  const float* bias = z == 0 ? qbq : z == 1 ? qbk : qbv;
  float* C = z == 0 ? Yq : z == 1 ? Yk : Yv;
  gemm_body(qX, Bm, C, bias, scal, S_X, S_WQ + z, S_YQ + z);
}

__global__ __launch_bounds__(256) void gemm_proj(const int8_t* __restrict__ A, const int8_t* __restrict__ Bm,
                                                 float* __restrict__ C, const float* __restrict__ bias,
                                                 unsigned* __restrict__ scal, int slotA, int slotB, int maxslot) {
  gemm_body(A, Bm, C, bias, scal, slotA, slotB, maxslot);
}

// ---------------- head re-layout + quant ----------------

__device__ __forceinline__ void qheads_qk_body(const float* __restrict__ Y, int* __restrict__ q,
                                               const unsigned* __restrict__ scal, int slot, int i) {
  float s = qscale(scal, slot);
  int d0 = (i & 15) * 4;
  int sI = (i >> 4) & 511;
  int bh = i >> 13;
  int h = bh % 12, b = bh / 12;
  const float* src = Y + ((size_t)(b * 512 + sI)) * 768 + h * 64 + d0;
  float4 v = *(const float4*)src;
  q[i] = qpack4(v.x, v.y, v.z, v.w, s);
}

__device__ __forceinline__ void qheads_v_body(const float* __restrict__ Y, int8_t* __restrict__ q,
                                              const unsigned* __restrict__ scal, int blkv) {
  __shared__ int8_t T[64][68];
  int bh = blkv >> 3, sb = blkv & 7;
  int b = bh / 12, h = bh % 12;
  float s = qscale(scal, S_YV);
  int d = threadIdx.x & 63, sl = threadIdx.x >> 6;
#pragma unroll
  for (int i = 0; i < 16; ++i) {
    int s_local = i * 4 + sl;
    float y = Y[((size_t)(b * 512 + sb * 64 + s_local)) * 768 + h * 64 + d];
    float tq = fminf(fmaxf(rintf(y / s), -QMAXF), QMAXF);
    T[d][s_local] = (int8_t)tq;
  }
  __syncthreads();
  int s4 = (threadIdx.x & 15) * 4, dl = threadIdx.x >> 4;
#pragma unroll
  for (int i = 0; i < 4; ++i) {
    int d_ = i * 16 + dl;
    int packed = (T[d_][s4] & 255) | ((T[d_][s4 + 1] & 255) << 8) |
                 ((T[d_][s4 + 2] & 255) << 16) | ((T[d_][s4 + 3] & 255) << 24);
    *(int*)(q + (size_t)bh * 32768 + (size_t)d_ * 512 + sb * 64 + s4) = packed;
  }
}

__global__ __launch_bounds__(256) void quant_heads_all(const float* __restrict__ Yq, int* __restrict__ qq,
                                                       const float* __restrict__ Yk, int* __restrict__ qk,
                                                       const float* __restrict__ Yv, int8_t* __restrict__ qvT,
                                                       const unsigned* __restrict__ scal) {
  int blk = blockIdx.x;
  if (blk < 3072)      qheads_qk_body(Yq, qq, scal, S_YQ, blk * 256 + threadIdx.x);
  else if (blk < 6144) qheads_qk_body(Yk, qk, scal, S_YK, (blk - 3072) * 256 + threadIdx.x);
  else                 qheads_v_body(Yv, qvT, scal, blk - 6144);
}

__global__ __launch_bounds__(256) void quant_heads_qk(const float* __restrict__ Y, int* __restrict__ q,
                                                      const unsigned* __restrict__ scal, int slot) {
  qheads_qk_body(Y, q, scal, slot, blockIdx.x * 256 + threadIdx.x);
}
__global__ __launch_bounds__(256) void quant_heads_v(const float* __restrict__ Y, int8_t* __restrict__ q,
                                                     const unsigned* __restrict__ scal) {
  qheads_v_body(Y, q, scal, blockIdx.x);
}

// ---------------- attention e-phase (R6/R10-proven 4-wave version, fallback pass2) ----------------

__device__ __forceinline__ void attn_e_phase(const int8_t* __restrict__ qbase,
                                             const int8_t* __restrict__ kbase,
                                             int rb, float pref, const PLA& pla,
                                             float (&v)[8][4], float (*red)[16], float& denom) {
  __shared__ float2 ae2[11];   // (a[i], a[i+1])
  __shared__ float2 mcs[11];   // (m[i], c[i])
  int t = threadIdx.x, lane = t & 63, w = t >> 6, l15 = lane & 15, kg = lane >> 4;
  if (t < 11) {
    ae2[t] = make_float2(pla.a[t], pla.a[t + 1]);
    mcs[t] = make_float2(pla.m[t], pla.c[t]);
  }
  i32x4 zero = {0, 0, 0, 0};
  i32x4 qf = *(const i32x4*)(qbase + (size_t)(rb * 16 + l15) * 64 + kg * 16);
  i32x4 acc[8];
#pragma unroll
  for (int i = 0; i < 8; ++i) {
    i32x4 kf = *(const i32x4*)(kbase + (size_t)((w * 8 + i) * 16 + l15) * 64 + kg * 16);
    acc[i] = __builtin_amdgcn_mfma_i32_16x16x64_i8(kf, qf, zero, 0, 0, 0);
  }
  float mx = -3.4e38f;
#pragma unroll
  for (int i = 0; i < 8; ++i)
#pragma unroll
    for (int r = 0; r < 4; ++r) {
      v[i][r] = (float)acc[i][r] * pref;
      mx = fmaxf(mx, v[i][r]);
    }
  mx = fmaxf(mx, __shfl_xor(mx, 16, 64));
  mx = fmaxf(mx, __shfl_xor(mx, 32, 64));
  if (lane < 16) red[w][l15] = mx;
  __syncthreads();                     // also covers ae2/mcs init
  float gm = fmaxf(fmaxf(red[0][l15], red[1][l15]), fmaxf(red[2][l15], red[3][l15]));
  __syncthreads();
  float s = 0.0f;
#pragma unroll
  for (int i = 0; i < 8; ++i)
#pragma unroll
    for (int r = 0; r < 4; ++r) {
      float x = v[i][r] - gm;
      float sh = rintf(x * 67108864.0f);
      sh = fmaxf(sh, -671088640.0f);
      sh = fminf(sh, 0.0f);
      float xc = sh * (1.0f / 67108864.0f);
      float tf = (xc + 10.0f) * 1.2f;
      int i0 = (int)tf;
      i0 = i0 > 10 ? 10 : i0;
      float2 ee = ae2[i0];
      int idx = i0 + ((i0 < 10 && xc >= ee.y) ? 1 : 0) - ((xc < ee.x) ? 1 : 0);
      float2 mc = mcs[idx];
      float e = mc.x * xc;   // no fma: contract off
      e = e + mc.y;
      v[i][r] = e;
      s += e;
    }
  s += __shfl_xor(s, 16, 64);
  s += __shfl_xor(s, 32, 64);
  if (lane < 16) red[w][l15] = s;
  __syncthreads();
  denom = (((red[0][l15] + red[1][l15]) + red[2][l15]) + red[3][l15]) + 1e-9f;
  __syncthreads();   // protect red reuse by subsequent calls
}

// ---------------- pass1: 2 units/block, split reduce arrays (R13-proven) ----------------

__global__ __launch_bounds__(256) void attn_pass1(const int8_t* __restrict__ qq,
                                                  const int8_t* __restrict__ qk,
                                                  int* __restrict__ q15w,
                                                  unsigned* __restrict__ scal, PLA pla) {
  __shared__ float2 ae2[11];
  __shared__ float2 mcs[11];
  __shared__ float redm[4][16];
  __shared__ float reds[4][16];
  int t = threadIdx.x, lane = t & 63, w = t >> 6, l15 = lane & 15, kg = lane >> 4;
  if (t < 11) {
    ae2[t] = make_float2(pla.a[t], pla.a[t + 1]);
    mcs[t] = make_float2(pla.m[t], pla.c[t]);
  }
  float pref = (qscale(scal, S_YQ) * qscale(scal, S_YK)) * 0.125f;
  float dmLocal = 3.4e38f;
  i32x4 zero = {0, 0, 0, 0};
#pragma unroll
  for (int k = 0; k < 2; ++k) {
    int unit = blockIdx.x * 2 + k, rb = unit & 31, bh = unit >> 5;
    const int8_t* qbase = qq + (size_t)bh * 32768;
    const int8_t* kbase = qk + (size_t)bh * 32768;
    i32x4 qf = *(const i32x4*)(qbase + (size_t)(rb * 16 + l15) * 64 + kg * 16);
    i32x4 acc[8];
#pragma unroll
    for (int i = 0; i < 8; ++i) {
      i32x4 kf = *(const i32x4*)(kbase + (size_t)((w * 8 + i) * 16 + l15) * 64 + kg * 16);
      acc[i] = __builtin_amdgcn_mfma_i32_16x16x64_i8(kf, qf, zero, 0, 0, 0);
    }
    float v[8][4];
    float mx = -3.4e38f;
#pragma unroll
    for (int i = 0; i < 8; ++i)
#pragma unroll
      for (int r = 0; r < 4; ++r) {
        v[i][r] = (float)acc[i][r] * pref;
        mx = fmaxf(mx, v[i][r]);
      }
    mx = fmaxf(mx, __shfl_xor(mx, 16, 64));
    mx = fmaxf(mx, __shfl_xor(mx, 32, 64));
    if (lane < 16) redm[w][l15] = mx;
    __syncthreads();                   // barrier A
    float gm = fmaxf(fmaxf(redm[0][l15], redm[1][l15]), fmaxf(redm[2][l15], redm[3][l15]));
    float s = 0.0f;
#pragma unroll
    for (int i = 0; i < 8; ++i)
#pragma unroll
      for (int r = 0; r < 4; ++r) {
        float x = v[i][r] - gm;
        float sh = rintf(x * 67108864.0f);
        sh = fmaxf(sh, -671088640.0f);
        sh = fminf(sh, 0.0f);
        float xc = sh * (1.0f / 67108864.0f);
        float tf = (xc + 10.0f) * 1.2f;
        int i0 = (int)tf;
        i0 = i0 > 10 ? 10 : i0;
        float2 ee = ae2[i0];
        int idx = i0 + ((i0 < 10 && xc >= ee.y) ? 1 : 0) - ((xc < ee.x) ? 1 : 0);
        float2 mc = mcs[idx];
        float e = mc.x * xc;   // no fma: contract off
        e = e + mc.y;
        v[i][r] = e;
        s += e;
      }
    s += __shfl_xor(s, 16, 64);
    s += __shfl_xor(s, 32, 64);
    if (lane < 16) reds[w][l15] = s;
    __syncthreads();                   // barrier B
    float denom = (((reds[0][l15] + reds[1][l15]) + reds[2][l15]) + reds[3][l15]) + 1e-9f;
    dmLocal = fminf(dmLocal, denom);
    if (q15w) {
      float rdn = refined_rcp(denom);
      int d[16];
#pragma unroll
      for (int i = 0; i < 8; ++i) {
        int q15i[4];
#pragma unroll
        for (int r = 0; r < 4; ++r) {
          float sm32 = fdiv_m(v[i][r] * 32768.0f, denom, rdn);
          q15i[r] = (int)fminf(fmaxf(rintf(sm32), -32768.0f), 32767.0f);
        }
        d[i * 2]     = (q15i[0] & 0xffff) | (q15i[1] << 16);
        d[i * 2 + 1] = (q15i[2] & 0xffff) | (q15i[3] << 16);
      }
      i32x4* q15v = (i32x4*)(q15w + (size_t)unit * 4096);
#pragma unroll
      for (int j = 0; j < 4; ++j) {
        i32x4 pk = { d[4 * j], d[4 * j + 1], d[4 * j + 2], d[4 * j + 3] };
        __builtin_nontemporal_store(pk, &q15v[j * 256 + t]);
      }
    }
  }
  float dm = dmLocal;
  dm = fminf(dm, __shfl_xor(dm, 1, 64));
  dm = fminf(dm, __shfl_xor(dm, 2, 64));
  dm = fminf(dm, __shfl_xor(dm, 4, 64));
  dm = fminf(dm, __shfl_xor(dm, 8, 64));
  dm = fminf(dm, __shfl_xor(dm, 16, 64));
  dm = fminf(dm, __shfl_xor(dm, 32, 64));
  if (t == 0) atomicMax(scal + S_DMIN, 0x7f800000u - __float_as_uint(dm));
}

__device__ __forceinline__ float derive_sp(const unsigned* scal, const PLA& pla) {
  float dmin = __uint_as_float(0x7f800000u - scal[S_DMIN]);
  float smm = pla.c[10] / dmin;
  float q15m = fminf(fmaxf(rintf(smm * 32768.0f), -32768.0f), 32767.0f);
  return fmaxf((q15m * (1.0f / 32768.0f)) / QMAXF, 1e-8f);
}

__device__ __forceinline__ void attn_pv_tail(const int8_t* __restrict__ vT, int8_t (*Ps)[528],
                                             unsigned* __restrict__ scal, float* __restrict__ ctx,
                                             int rb, int bh, float sp) {
  int t = threadIdx.x, lane = t & 63, w = t >> 6, l15 = lane & 15, kg = lane >> 4;
  int b = bh / 12, h = bh % 12;
  float sv = qscale(scal, S_YV);
  i32x4 pacc = {0, 0, 0, 0};
  const int8_t* vbase = vT + (size_t)bh * 32768 + (size_t)(w * 16 + l15) * 512;
#pragma unroll
  for (int ks = 0; ks < 8; ++ks) {
    i32x4 pf = *(const i32x4*)&Ps[l15][ks * 64 + kg * 16];
    i32x4 vf = *(const i32x4*)(vbase + ks * 64 + kg * 16);
    pacc = __builtin_amdgcn_mfma_i32_16x16x64_i8(pf, vf, pacc, 0, 0, 0);
  }
  float spv = sp * sv;
  float am = 0.0f;
#pragma unroll
  for (int r = 0; r < 4; ++r) {
    int srow = rb * 16 + kg * 4 + r;
    float val = (float)pacc[r] * spv;
    ctx[((size_t)(b * 512 + srow)) * 768 + h * 64 + w * 16 + l15] = val;
    am = fmaxf(am, fabsf(val));
  }
  block_atomic_maxf(am, scal + S_CTX);
}

// ---------------- pass2_load: 2 units/block, prefetch both q15 tiles, shared V-tile ----------------
// unit0 = 2*blk is even, so unit0 and unit0+1 always share bh (crossing a 32-boundary would
// require odd unit0) -> V-tile is L2/L1-warm for unit 1. Both units' q15 nt-loads issue at
// entry; unit1's HBM latency hides under unit0's requant+PV. Requant/PV math identical to R13.

__global__ __launch_bounds__(256) void attn_pass2_load(const int* __restrict__ q15r,
                                                       const int8_t* __restrict__ vT,
                                                       unsigned* __restrict__ scal,
                                                       float* __restrict__ ctx, PLA pla) {
  __shared__ alignas(16) int8_t Ps[16][528];
  int t = threadIdx.x, lane = t & 63, w = t >> 6, l15 = lane & 15, kg = lane >> 4;
  int unit0 = blockIdx.x * 2;
  int bh = unit0 >> 5;
  int b = bh / 12, h = bh % 12;
  float sp = derive_sp(scal, pla);
  float rsp = refined_rcp(sp);
  float sv = qscale(scal, S_YV);
  float spv = sp * sv;
  const i32x4* q0p = (const i32x4*)(q15r + (size_t)unit0 * 4096);
  const i32x4* q1p = (const i32x4*)(q15r + (size_t)(unit0 + 1) * 4096);
  i32x4 pk0[4], pk1[4];
#pragma unroll
  for (int j = 0; j < 4; ++j) {
    pk0[j] = __builtin_nontemporal_load(&q0p[j * 256 + t]);
    pk1[j] = __builtin_nontemporal_load(&q1p[j * 256 + t]);
  }
  const int8_t* vbase = vT + (size_t)bh * 32768 + (size_t)(w * 16 + l15) * 512;
  float am = 0.0f;
#pragma unroll
  for (int u = 0; u < 2; ++u) {
    int rb = (unit0 + u) & 31;
#pragma unroll
    for (int i = 0; i < 8; ++i) {
      int jj = i >> 1, e0 = (i & 1) * 2;
      int u01 = u ? pk1[jj][e0] : pk0[jj][e0];
      int u23 = u ? pk1[jj][e0 + 1] : pk0[jj][e0 + 1];
      int q15i[4] = { (int)(short)(u01 & 0xffff), u01 >> 16,
                      (int)(short)(u23 & 0xffff), u23 >> 16 };
      uint32_t packed = 0;
#pragma unroll
      for (int r = 0; r < 4; ++r) {
        float pv = (float)q15i[r] * (1.0f / 32768.0f);
        int qp = (int)fminf(fmaxf(rintf(fdiv_m(pv, sp, rsp)), -QMAXF), QMAXF);
        packed |= (uint32_t)(qp & 255) << (8 * r);
      }
      *(uint32_t*)&Ps[l15][(w * 8 + i) * 16 + kg * 4] = packed;
    }
    __syncthreads();                   // Ps(u) complete
    i32x4 pacc = {0, 0, 0, 0};
#pragma unroll
    for (int ks = 0; ks < 8; ++ks) {
      i32x4 pf = *(const i32x4*)&Ps[l15][ks * 64 + kg * 16];
      i32x4 vf = *(const i32x4*)(vbase + ks * 64 + kg * 16);
      pacc = __builtin_amdgcn_mfma_i32_16x16x64_i8(pf, vf, pacc, 0, 0, 0);
    }
#pragma unroll
    for (int r = 0; r < 4; ++r) {
      int srow = rb * 16 + kg * 4 + r;
      float val = (float)pacc[r] * spv;
      ctx[((size_t)(b * 512 + srow)) * 768 + h * 64 + w * 16 + l15] = val;
      am = fmaxf(am, fabsf(val));
    }
    __syncthreads();                   // PV(u) reads done before Ps(u+1) writes
  }
  block_atomic_maxf(am, scal + S_CTX);
}

// fallback pass2: recompute e-phase, quantize, PV (R6 path)
__global__ __launch_bounds__(256) void attn_pass2_recompute(const int8_t* __restrict__ qq,
                                                            const int8_t* __restrict__ qk,
                                                            const int8_t* __restrict__ vT,
                                                            unsigned* __restrict__ scal,
                                                            float* __restrict__ ctx, PLA pla) {
  __shared__ float red[4][16];
  __shared__ alignas(16) int8_t Ps[16][528];
  int rb = blockIdx.x & 31, bh = blockIdx.x >> 5;
  float pref = (qscale(scal, S_YQ) * qscale(scal, S_YK)) * 0.125f;
  float sp = derive_sp(scal, pla);
  float rsp = refined_rcp(sp);
  float v[8][4];
  float denom;
  attn_e_phase(qq + (size_t)bh * 32768, qk + (size_t)bh * 32768, rb, pref, pla, v, red, denom);
  float rdn = refined_rcp(denom);
  int t = threadIdx.x, lane = t & 63, w = t >> 6, l15 = lane & 15, kg = lane >> 4;
#pragma unroll
  for (int i = 0; i < 8; ++i) {
    uint32_t packed = 0;
#pragma unroll
    for (int r = 0; r < 4; ++r) {
      float sm32 = fdiv_m(v[i][r] * 32768.0f, denom, rdn);
      float q15 = fminf(fmaxf(rintf(sm32), -32768.0f), 32767.0f);
      float pv = q15 * (1.0f / 32768.0f);
      int qp = (int)fminf(fmaxf(rintf(fdiv_m(pv, sp, rsp)), -QMAXF), QMAXF);
      packed |= (uint32_t)(qp & 255) << (8 * r);
    }
    *(uint32_t*)&Ps[l15][(w * 8 + i) * 16 + kg * 4] = packed;
  }
  __syncthreads();
  attn_pv_tail(vT, Ps, scal, ctx, rb, bh, sp);
}

// ---------------- collapsed ctx double-quant + qbias_o (R9-proven) ----------------
// q2 == q0 identity (R8-proven): with ctxq1max = fl(127*s1), s2 = s1*(1 +- 1ulp), so
// rint(q0*s1/s2) == q0 for |q0|<=127. qctx2 = q0 directly; S_CTXQ1 <- fl(127*s1).

__global__ __launch_bounds__(256) void ctx_q12_plus(const float4* __restrict__ ctx, int* __restrict__ q2o,
                                                    const float* __restrict__ bo, float* __restrict__ qbo,
                                                    unsigned* __restrict__ scal) {
  int blk = blockIdx.x;
  float s1 = qscale(scal, S_CTX);
  float ctxq1max = 127.0f * s1;
  if (blk < 3072) {
    float rs1 = refined_rcp(s1);
    int i = blk * 256 + threadIdx.x;
    float4 c = ctx[i];
    int q0 = (int)fminf(fmaxf(rintf(fdiv_m(c.x, s1, rs1)), -QMAXF), QMAXF);
    int q1 = (int)fminf(fmaxf(rintf(fdiv_m(c.y, s1, rs1)), -QMAXF), QMAXF);
    int q2 = (int)fminf(fmaxf(rintf(fdiv_m(c.z, s1, rs1)), -QMAXF), QMAXF);
    int q3 = (int)fminf(fmaxf(rintf(fdiv_m(c.w, s1, rs1)), -QMAXF), QMAXF);
    q2o[i] = (q0 & 255) | ((q1 & 255) << 8) | ((q2 & 255) << 16) | ((q3 & 255) << 24);
  } else {
    if (blk == 3072 && threadIdx.x == 0) scal[S_CTXQ1] = __float_as_uint(ctxq1max);
    int j = (blk - 3072) * 256 + threadIdx.x;
    if (j < 768) {
      float in_scale = ctxq1max / QMAXF;   // no clamp (reference)
      float w_scale = __uint_as_float(scal[S_WO]) / QMAXF;
      float bias_scale = in_scale * w_scale;
      float tmax = __uint_as_float(scal[S_BO]) / bias_scale;
      float st = fmaxf(tmax / QMAXF, 1e-8f);
      float tv = bo[j] / bias_scale;
      float qv = fminf(fmaxf(rintf(tv / st), -127.0f), 127.0f) * st;
      qbo[j] = qv * bias_scale;
    }
  }
}

// ---------------- host: PLA build (replicates np.polyfit degree-1 LS in f64) ----------------

static void build_pla(PLA& p) {
  double xs[1001], ys[1001];
  double step = 10.0 / 1000.0;
  for (int j = 0; j <= 1000; ++j) xs[j] = (double)j * step + (-10.0);
  xs[1000] = 0.0;
  for (int j = 0; j <= 1000; ++j) ys[j] = exp(xs[j]);
  double estep = 10.0 / 12.0;
  for (int i = 0; i < 12; ++i) {
    double a = (double)i * estep + (-10.0);
    double bb = (i + 1 == 12) ? 0.0 : (double)(i + 1) * estep + (-10.0);
    double n = 0, Sx = 0, Sy = 0, Sxx = 0, Sxy = 0;
    for (int j = 0; j <= 1000; ++j) {
      if (xs[j] >= a && xs[j] <= bb) {
        double x = xs[j], y = ys[j];
        n += 1.0; Sx += x; Sy += y; Sxx += x * x; Sxy += x * y;
      }
    }
    double det = n * Sxx - Sx * Sx;
    p.m[i] = (float)((n * Sxy - Sx * Sy) / det);
    p.c[i] = (float)((Sxx * Sy - Sx * Sxy) / det);
    p.a[i] = (float)a;
  }
}

// ---------------- launch ----------------

extern "C" void kernel_launch(void* const* d_in, const int* in_sizes, int n_in,
                              void* d_out, int out_size, void* d_ws, size_t ws_size,
                              hipStream_t stream) {
  const float* X  = (const float*)d_in[0];
  const float* Wq = (const float*)d_in[1];
  const float* bq = (const float*)d_in[2];
  const float* Wk = (const float*)d_in[3];
  const float* bk = (const float*)d_in[4];
  const float* Wv = (const float*)d_in[5];
  const float* bv = (const float*)d_in[6];
  const float* Wo = (const float*)d_in[7];
  const float* bo = (const float*)d_in[8];
  float* out = (float*)d_out;
  (void)n_in; (void)in_sizes; (void)out_size;

  PLA pla;
  build_pla(pla);

  const size_t NX = 8 * 512 * 768;   // 3145728
  const size_t NW = 768 * 768;       // 589824
  const size_t Q15_BYTES = 3072ull * 16384;  // 48 MiB

  uint8_t* ws = (uint8_t*)d_ws;
  size_t off = 0;
  auto alloc = [&](size_t bytes) -> void* {
    void* p = ws + off;
    off += (bytes + 255) & ~(size_t)255;
    return p;
  };

  unsigned* scal = (unsigned*)alloc(256);
  int8_t* qWq = (int8_t*)alloc(NW);
  int8_t* qWk = (int8_t*)alloc(NW);
  int8_t* qWv = (int8_t*)alloc(NW);
  int8_t* qWo = (int8_t*)alloc(NW);
  float* qbq = (float*)alloc(768 * 4);
  float* qbk = (float*)alloc(768 * 4);
  float* qbv = (float*)alloc(768 * 4);
  float* qbo = (float*)alloc(768 * 4);
  int8_t* qX = (int8_t*)alloc(NX);       // reused as qctx2
  int8_t* qctx2 = qX;

  size_t fixed = off;
  size_t need_fast = fixed + Q15_BYTES + (4 * NX) + NX + 512;
  bool fast = ws_size >= need_fast;

  hipMemsetAsync(scal, 0, 256, stream);

  if (fast) {
    uint8_t* D = (uint8_t*)alloc(Q15_BYTES);        // Yq|Yk|Yv then q15
    float* Yq = (float*)D;
    float* Yk = (float*)(D + NX * 4);
    float* Yv = (float*)(D + 2 * NX * 4);
    int* q15buf = (int*)D;
    uint8_t* E = (uint8_t*)alloc(4 * NX);           // qq|qk then ctx
    int8_t* qq = (int8_t*)E;
    int8_t* qk = (int8_t*)(E + NX);
    float* ctx = (float*)E;
    int8_t* qvT = (int8_t*)alloc(NX);

    maxabs_all<<<1604, 256, 0, stream>>>((const float4*)X, (const float4*)Wq, (const float4*)Wk,
                                         (const float4*)Wv, (const float4*)Wo, bq, bk, bv, bo, scal);
    quant_all<<<1609, 256, 0, stream>>>((const float4*)X, (int*)qX,
                                        (const float4*)Wq, (const float4*)Wk, (const float4*)Wv, (const float4*)Wo,
                                        (int*)qWq, (int*)qWk, (int*)qWv, (int*)qWo,
                                        bq, bk, bv, qbq, qbk, qbv, scal);
    gemm_qkv<<<dim3(12, 32, 3), 256, 0, stream>>>(qX, qWq, qWk, qWv, qbq, qbk, qbv, Yq, Yk, Yv, scal);
    quant_heads_all<<<6912, 256, 0, stream>>>(Yq, (int*)qq, Yk, (int*)qk, Yv, qvT, scal);
    attn_pass1<<<1536, 256, 0, stream>>>(qq, qk, q15buf, scal, pla);         // q15 overwrites Y (dead)
    attn_pass2_load<<<1536, 256, 0, stream>>>(q15buf, qvT, scal, ctx, pla);  // ctx overwrites qq/qk (dead)
    ctx_q12_plus<<<3075, 256, 0, stream>>>((const float4*)ctx, (int*)qctx2, bo, qbo, scal);
    gemm_proj<<<dim3(12, 32), 256, 0, stream>>>(qctx2, qWo, out, qbo, scal, S_CTXQ1, S_WO, -1);
  } else {
    float* Y = (float*)alloc(NX * 4);               // then ctx
    float* ctx = Y;
    int8_t* qq = (int8_t*)alloc(NX);
    int8_t* qk = (int8_t*)alloc(NX);
    int8_t* qvT = (int8_t*)alloc(NX);

    maxabs_all<<<1604, 256, 0, stream>>>((const float4*)X, (const float4*)Wq, (const float4*)Wk,
                                         (const float4*)Wv, (const float4*)Wo, bq, bk, bv, bo, scal);
    quant_all<<<1609, 256, 0, stream>>>((const float4*)X, (int*)qX,
                                        (const float4*)Wq, (const float4*)Wk, (const float4*)Wv, (const float4*)Wo,
                                        (int*)qWq, (int*)qWk, (int*)qWv, (int*)qWo,
                                        bq, bk, bv, qbq, qbk, qbv, scal);
    gemm_proj<<<dim3(12, 32), 256, 0, stream>>>(qX, qWq, Y, qbq, scal, S_X, S_WQ, S_YQ);
    quant_heads_qk<<<3072, 256, 0, stream>>>(Y, (int*)qq, scal, S_YQ);
    gemm_proj<<<dim3(12, 32), 256, 0, stream>>>(qX, qWk, Y, qbk, scal, S_X, S_WK, S_YK);
    quant_heads_qk<<<3072, 256, 0, stream>>>(Y, (int*)qk, scal, S_YK);
    gemm_proj<<<dim3(12, 32), 256, 0, stream>>>(qX, qWv, Y, qbv, scal, S_X, S_WV, S_YV);
    quant_heads_v<<<768, 256, 0, stream>>>(Y, qvT, scal);
    attn_pass1<<<1536, 256, 0, stream>>>(qq, qk, (int*)nullptr, scal, pla);
    attn_pass2_recompute<<<3072, 256, 0, stream>>>(qq, qk, qvT, scal, ctx, pla);
    ctx_q12_plus<<<3075, 256, 0, stream>>>((const float4*)ctx, (int*)qctx2, bo, qbo, scal);
    gemm_proj<<<dim3(12, 32), 256, 0, stream>>>(qctx2, qWo, out, qbo, scal, S_CTXQ1, S_WO, -1);
  }
}

// Round 15
// 141.905 us; speedup vs baseline: 1.2419x; 1.0629x over previous
//
#include <hip/hip_runtime.h>
#include <cstdint>
#include <cmath>
#include <cstddef>

#pragma clang fp contract(off)

#define QMAXF 127.0f

typedef int i32x4 __attribute__((ext_vector_type(4)));

enum {
  S_X = 0, S_WQ, S_WK, S_WV, S_WO, S_BQ, S_BK, S_BV, S_BO,
  S_YQ, S_YK, S_YV, S_CTX, S_CTXQ1, S_DMIN, S_PAD
};

struct PLA { float m[12]; float c[12]; float a[12]; };

#define GLOAD_LDS16(gsrc, ldst) \
  __builtin_amdgcn_global_load_lds((const __attribute__((address_space(1))) void*)(gsrc), \
                                   (__attribute__((address_space(3))) void*)(ldst), 16, 0, 0)

// ---------------- device helpers ----------------

__device__ __forceinline__ float qscale(const unsigned* scal, int slot) {
  // reference: scale = max(maxabs / 127.0, 1e-8)
  return fmaxf(__uint_as_float(scal[slot]) / QMAXF, 1e-8f);
}

// Markstein correctly-rounded division with hoisted refined reciprocal (validated R6/R8).
__device__ __forceinline__ float refined_rcp(float d) {
  float rd = __builtin_amdgcn_rcpf(d);
  return fmaf(fmaf(-d, rd, 1.0f), rd, rd);
}
__device__ __forceinline__ float fdiv_m(float v, float d, float rd) {
  float q0 = v * rd;
  float r = fmaf(-d, q0, v);
  return fmaf(r, rd, q0);
}

__device__ __forceinline__ void block_atomic_maxf(float v, unsigned* slot) {
  for (int off = 32; off > 0; off >>= 1) v = fmaxf(v, __shfl_xor(v, off, 64));
  __shared__ float red4[4];
  int lane = threadIdx.x & 63, w = threadIdx.x >> 6;
  if (lane == 0) red4[w] = v;
  __syncthreads();
  if (threadIdx.x == 0)
    atomicMax(slot, __float_as_uint(fmaxf(fmaxf(red4[0], red4[1]), fmaxf(red4[2], red4[3]))));
}

__device__ __forceinline__ int qpack4(float a0, float a1, float a2, float a3, float s) {
  int i0 = (int)fminf(fmaxf(rintf(a0 / s), -QMAXF), QMAXF);
  int i1 = (int)fminf(fmaxf(rintf(a1 / s), -QMAXF), QMAXF);
  int i2 = (int)fminf(fmaxf(rintf(a2 / s), -QMAXF), QMAXF);
  int i3 = (int)fminf(fmaxf(rintf(a3 / s), -QMAXF), QMAXF);
  return (i0 & 255) | ((i1 & 255) << 8) | ((i2 & 255) << 16) | ((i3 & 255) << 24);
}

__device__ __forceinline__ float fabs4max(float4 v) {
  return fmaxf(fmaxf(fabsf(v.x), fabsf(v.y)), fmaxf(fabsf(v.z), fabsf(v.w)));
}

// ---------------- scal init (replaces hipMemsetAsync: fillBuffer showed 42us in-graph) ------

__global__ void zero_scal(unsigned* __restrict__ s) {
  if (threadIdx.x < 64) s[threadIdx.x] = 0u;
}

// ---------------- fused maxabs: X + 4 weights + 4 biases ----------------

__global__ __launch_bounds__(256) void maxabs_all(const float4* __restrict__ X,
                                                  const float4* __restrict__ w0, const float4* __restrict__ w1,
                                                  const float4* __restrict__ w2, const float4* __restrict__ w3,
                                                  const float* __restrict__ b0, const float* __restrict__ b1,
                                                  const float* __restrict__ b2, const float* __restrict__ b3,
                                                  unsigned* __restrict__ scal) {
  int blk = blockIdx.x, t = threadIdx.x;
  float m = 0.0f;
  unsigned* slot;
  if (blk < 1024) {
    int i = blk * 256 + t;
#pragma unroll
    for (int k = 0; k < 3; ++k) m = fmaxf(m, fabs4max(X[i + k * 262144]));
    slot = scal + S_X;
  } else if (blk < 1600) {
    int which = (blk - 1024) / 144, j = (blk - 1024) % 144;
    const float4* p = which == 0 ? w0 : which == 1 ? w1 : which == 2 ? w2 : w3;
    int i = j * 256 + t;
#pragma unroll
    for (int k = 0; k < 4; ++k) m = fmaxf(m, fabs4max(p[i + k * 36864]));
    slot = scal + S_WQ + which;
  } else {
    int which = blk - 1600;
    const float* p = which == 0 ? b0 : which == 1 ? b1 : which == 2 ? b2 : b3;
    for (int i = t; i < 768; i += 256) m = fmaxf(m, fabsf(p[i]));
    slot = scal + S_BQ + which;
  }
  block_atomic_maxf(m, slot);
}

// ---------------- fused quant: X + 4 weights + qbias(q,k,v) ----------------

__device__ __forceinline__ void qbias_body(const float* __restrict__ b, float* __restrict__ qb,
                                           const unsigned* __restrict__ scal, int slotX, int slotW, int slotB, int j) {
  if (j >= 768) return;
  float in_scale = __uint_as_float(scal[slotX]) / QMAXF;   // no clamp (reference)
  float w_scale  = __uint_as_float(scal[slotW]) / QMAXF;
  float bias_scale = in_scale * w_scale;
  float tmax = __uint_as_float(scal[slotB]) / bias_scale;
  float st = fmaxf(tmax / QMAXF, 1e-8f);
  float t = b[j] / bias_scale;
  float qv = fminf(fmaxf(rintf(t / st), -127.0f), 127.0f) * st;
  qb[j] = qv * bias_scale;
}

__global__ __launch_bounds__(256) void quant_all(const float4* __restrict__ X, int* __restrict__ qX,
                                                 const float4* __restrict__ w0, const float4* __restrict__ w1,
                                                 const float4* __restrict__ w2, const float4* __restrict__ w3,
                                                 int* __restrict__ o0, int* __restrict__ o1,
                                                 int* __restrict__ o2, int* __restrict__ o3,
                                                 const float* __restrict__ bq, const float* __restrict__ bk,
                                                 const float* __restrict__ bv,
                                                 float* __restrict__ qbq, float* __restrict__ qbk,
                                                 float* __restrict__ qbv,
                                                 const unsigned* __restrict__ scal) {
  int blk = blockIdx.x, t = threadIdx.x;
  if (blk < 1024) {
    float s = qscale(scal, S_X);
    int i = blk * 256 + t;
#pragma unroll
    for (int k = 0; k < 3; ++k) {
      float4 v = X[i + k * 262144];
      qX[i + k * 262144] = qpack4(v.x, v.y, v.z, v.w, s);
    }
  } else if (blk < 1600) {
    int which = (blk - 1024) / 144, j = (blk - 1024) % 144;
    const float4* p = which == 0 ? w0 : which == 1 ? w1 : which == 2 ? w2 : w3;
    int* o = which == 0 ? o0 : which == 1 ? o1 : which == 2 ? o2 : o3;
    float s = qscale(scal, S_WQ + which);
    int i = j * 256 + t;
#pragma unroll
    for (int k = 0; k < 4; ++k) {
      float4 v = p[i + k * 36864];
      o[i + k * 36864] = qpack4(v.x, v.y, v.z, v.w, s);
    }
  } else {
    int proj = (blk - 1600) / 3, part = (blk - 1600) % 3;
    int j = part * 256 + t;
    const float* b = proj == 0 ? bq : proj == 1 ? bk : bv;
    float* qb = proj == 0 ? qbq : proj == 1 ? qbk : qbv;
    qbias_body(b, qb, scal, S_X, S_WQ + proj, S_BQ + proj, j);
  }
}

// ---------------- LDS-staged MFMA int8 GEMM (proven R5/R6 structure) ----------------

__device__ __forceinline__ void gemm_body(const int8_t* __restrict__ A, const int8_t* __restrict__ Bm,
                                          float* __restrict__ C, const float* __restrict__ bias,
                                          unsigned* __restrict__ scal, int slotA, int slotB, int maxslot) {
  __shared__ int8_t Al[16384];
  __shared__ int8_t Bl[8192];
  int t = threadIdx.x, lane = t & 63, w = t >> 6, l15 = lane & 15, kg4 = lane >> 4;
  int bm = blockIdx.y * 128, bn = blockIdx.x * 64;
  float sAB = qscale(scal, slotA) * qscale(scal, slotB);
  int srow = t >> 3, scol = (t & 7) * 16;
  int ssw = scol ^ ((srow & 7) << 4);
  i32x4 acc[2][4];
#pragma unroll
  for (int rt = 0; rt < 2; ++rt)
#pragma unroll
    for (int ct = 0; ct < 4; ++ct)
#pragma unroll
      for (int r = 0; r < 4; ++r) acc[rt][ct][r] = 0;

  for (int kt = 0; kt < 6; ++kt) {
    int kc = kt * 128;
#pragma unroll
    for (int j = 0; j < 4; ++j) {
      int r = j * 32 + srow;
      GLOAD_LDS16(A + (size_t)(bm + r) * 768 + kc + ssw, Al + r * 128 + scol);
    }
#pragma unroll
    for (int j = 0; j < 2; ++j) {
      int r = j * 32 + srow;
      GLOAD_LDS16(Bm + (size_t)(bn + r) * 768 + kc + ssw, Bl + r * 128 + scol);
    }
    __syncthreads();
#pragma unroll
    for (int kg = 0; kg < 2; ++kg) {
      int kcol = kg * 64 + kg4 * 16;
      i32x4 af[2], bf[4];
#pragma unroll
      for (int rt = 0; rt < 2; ++rt) {
        int ar = w * 32 + rt * 16 + l15;
        af[rt] = *(const i32x4*)(Al + ar * 128 + (kcol ^ ((ar & 7) << 4)));
      }
#pragma unroll
      for (int ct = 0; ct < 4; ++ct) {
        int br = ct * 16 + l15;
        bf[ct] = *(const i32x4*)(Bl + br * 128 + (kcol ^ ((br & 7) << 4)));
      }
#pragma unroll
      for (int rt = 0; rt < 2; ++rt)
#pragma unroll
        for (int ct = 0; ct < 4; ++ct)
          acc[rt][ct] = __builtin_amdgcn_mfma_i32_16x16x64_i8(af[rt], bf[ct], acc[rt][ct], 0, 0, 0);
    }
    __syncthreads();
  }
  float am = 0.0f;
#pragma unroll
  for (int rt = 0; rt < 2; ++rt)
#pragma unroll
    for (int ct = 0; ct < 4; ++ct) {
      int col = bn + ct * 16 + l15;
      float bv = bias[col];
#pragma unroll
      for (int r = 0; r < 4; ++r) {
        int row = bm + w * 32 + rt * 16 + kg4 * 4 + r;
        float v = (float)acc[rt][ct][r] * sAB;
        float yv = v + bv;
        C[(size_t)row * 768 + col] = yv;
        am = fmaxf(am, fabsf(yv));
      }
    }
  if (maxslot >= 0) block_atomic_maxf(am, scal + maxslot);
}

__global__ __launch_bounds__(256) void gemm_qkv(const int8_t* __restrict__ qX,
                                                const int8_t* __restrict__ qWq, const int8_t* __restrict__ qWk,
                                                const int8_t* __restrict__ qWv,
                                                const float* __restrict__ qbq, const float* __restrict__ qbk,
                                                const float* __restrict__ qbv,
                                                float* __restrict__ Yq, float* __restrict__ Yk, float* __restrict__ Yv,
                                                unsigned* __restrict__ scal) {
  int z = blockIdx.z;
  const int8_t* Bm = z == 0 ? qWq : z == 1 ? qWk : qWv;
  const float* bias = z == 0 ? qbq : z == 1 ? qbk : qbv;
  float* C = z == 0 ? Yq : z == 1 ? Yk : Yv;
  gemm_body(qX, Bm, C, bias, scal, S_X, S_WQ + z, S_YQ + z);
}

__global__ __launch_bounds__(256) void gemm_proj(const int8_t* __restrict__ A, const int8_t* __restrict__ Bm,
                                                 float* __restrict__ C, const float* __restrict__ bias,
                                                 unsigned* __restrict__ scal, int slotA, int slotB, int maxslot) {
  gemm_body(A, Bm, C, bias, scal, slotA, slotB, maxslot);
}

// ---------------- head re-layout + quant ----------------

__device__ __forceinline__ void qheads_qk_body(const float* __restrict__ Y, int* __restrict__ q,
                                               const unsigned* __restrict__ scal, int slot, int i) {
  float s = qscale(scal, slot);
  int d0 = (i & 15) * 4;
  int sI = (i >> 4) & 511;
  int bh = i >> 13;
  int h = bh % 12, b = bh / 12;
  const float* src = Y + ((size_t)(b * 512 + sI)) * 768 + h * 64 + d0;
  float4 v = *(const float4*)src;
  q[i] = qpack4(v.x, v.y, v.z, v.w, s);
}

__device__ __forceinline__ void qheads_v_body(const float* __restrict__ Y, int8_t* __restrict__ q,
                                              const unsigned* __restrict__ scal, int blkv) {
  __shared__ int8_t T[64][68];
  int bh = blkv >> 3, sb = blkv & 7;
  int b = bh / 12, h = bh % 12;
  float s = qscale(scal, S_YV);
  int d = threadIdx.x & 63, sl = threadIdx.x >> 6;
#pragma unroll
  for (int i = 0; i < 16; ++i) {
    int s_local = i * 4 + sl;
    float y = Y[((size_t)(b * 512 + sb * 64 + s_local)) * 768 + h * 64 + d];
    float tq = fminf(fmaxf(rintf(y / s), -QMAXF), QMAXF);
    T[d][s_local] = (int8_t)tq;
  }
  __syncthreads();
  int s4 = (threadIdx.x & 15) * 4, dl = threadIdx.x >> 4;
#pragma unroll
  for (int i = 0; i < 4; ++i) {
    int d_ = i * 16 + dl;
    int packed = (T[d_][s4] & 255) | ((T[d_][s4 + 1] & 255) << 8) |
                 ((T[d_][s4 + 2] & 255) << 16) | ((T[d_][s4 + 3] & 255) << 24);
    *(int*)(q + (size_t)bh * 32768 + (size_t)d_ * 512 + sb * 64 + s4) = packed;
  }
}

__global__ __launch_bounds__(256) void quant_heads_all(const float* __restrict__ Yq, int* __restrict__ qq,
                                                       const float* __restrict__ Yk, int* __restrict__ qk,
                                                       const float* __restrict__ Yv, int8_t* __restrict__ qvT,
                                                       const unsigned* __restrict__ scal) {
  int blk = blockIdx.x;
  if (blk < 3072)      qheads_qk_body(Yq, qq, scal, S_YQ, blk * 256 + threadIdx.x);
  else if (blk < 6144) qheads_qk_body(Yk, qk, scal, S_YK, (blk - 3072) * 256 + threadIdx.x);
  else                 qheads_v_body(Yv, qvT, scal, blk - 6144);
}

__global__ __launch_bounds__(256) void quant_heads_qk(const float* __restrict__ Y, int* __restrict__ q,
                                                      const unsigned* __restrict__ scal, int slot) {
  qheads_qk_body(Y, q, scal, slot, blockIdx.x * 256 + threadIdx.x);
}
__global__ __launch_bounds__(256) void quant_heads_v(const float* __restrict__ Y, int8_t* __restrict__ q,
                                                     const unsigned* __restrict__ scal) {
  qheads_v_body(Y, q, scal, blockIdx.x);
}

// ---------------- attention e-phase (R6-proven 4-wave version, fallback pass2 only) ----------------

__device__ __forceinline__ void attn_e_phase(const int8_t* __restrict__ qbase,
                                             const int8_t* __restrict__ kbase,
                                             int rb, float pref, const PLA& pla,
                                             float (&v)[8][4], float (*red)[16], float& denom) {
  __shared__ float2 ae2[11];   // (a[i], a[i+1])
  __shared__ float2 mcs[11];   // (m[i], c[i])
  int t = threadIdx.x, lane = t & 63, w = t >> 6, l15 = lane & 15, kg = lane >> 4;
  if (t < 11) {
    ae2[t] = make_float2(pla.a[t], pla.a[t + 1]);
    mcs[t] = make_float2(pla.m[t], pla.c[t]);
  }
  i32x4 zero = {0, 0, 0, 0};
  i32x4 qf = *(const i32x4*)(qbase + (size_t)(rb * 16 + l15) * 64 + kg * 16);
  i32x4 acc[8];
#pragma unroll
  for (int i = 0; i < 8; ++i) {
    i32x4 kf = *(const i32x4*)(kbase + (size_t)((w * 8 + i) * 16 + l15) * 64 + kg * 16);
    acc[i] = __builtin_amdgcn_mfma_i32_16x16x64_i8(kf, qf, zero, 0, 0, 0);
  }
  float mx = -3.4e38f;
#pragma unroll
  for (int i = 0; i < 8; ++i)
#pragma unroll
    for (int r = 0; r < 4; ++r) {
      v[i][r] = (float)acc[i][r] * pref;
      mx = fmaxf(mx, v[i][r]);
    }
  mx = fmaxf(mx, __shfl_xor(mx, 16, 64));
  mx = fmaxf(mx, __shfl_xor(mx, 32, 64));
  if (lane < 16) red[w][l15] = mx;
  __syncthreads();                     // also covers ae2/mcs init
  float gm = fmaxf(fmaxf(red[0][l15], red[1][l15]), fmaxf(red[2][l15], red[3][l15]));
  __syncthreads();
  float s = 0.0f;
#pragma unroll
  for (int i = 0; i < 8; ++i)
#pragma unroll
    for (int r = 0; r < 4; ++r) {
      float x = v[i][r] - gm;
      float sh = rintf(x * 67108864.0f);
      sh = fmaxf(sh, -671088640.0f);
      sh = fminf(sh, 0.0f);
      float xc = sh * (1.0f / 67108864.0f);
      float tf = (xc + 10.0f) * 1.2f;
      int i0 = (int)tf;
      i0 = i0 > 10 ? 10 : i0;
      float2 ee = ae2[i0];
      int idx = i0 + ((i0 < 10 && xc >= ee.y) ? 1 : 0) - ((xc < ee.x) ? 1 : 0);
      float2 mc = mcs[idx];
      float e = mc.x * xc;   // no fma: contract off
      e = e + mc.y;
      v[i][r] = e;
      s += e;
    }
  s += __shfl_xor(s, 16, 64);
  s += __shfl_xor(s, 32, 64);
  if (lane < 16) red[w][l15] = s;
  __syncthreads();
  denom = (((red[0][l15] + red[1][l15]) + red[2][l15]) + red[3][l15]) + 1e-9f;
  __syncthreads();   // protect red reuse by subsequent calls
}

// ---------------- pass1: 4 units/block (all share bh -> K-tile reuse), split reduce arrays ----
// Arithmetic instruction-identical to attn_e_phase; q15 contract: unit*4096, thread-major
// dwordx4, nontemporal. 2 barriers/unit (alternating redm/reds arrays, R13-proven).

__global__ __launch_bounds__(256) void attn_pass1(const int8_t* __restrict__ qq,
                                                  const int8_t* __restrict__ qk,
                                                  int* __restrict__ q15w,
                                                  unsigned* __restrict__ scal, PLA pla) {
  __shared__ float2 ae2[11];
  __shared__ float2 mcs[11];
  __shared__ float redm[4][16];
  __shared__ float reds[4][16];
  int t = threadIdx.x, lane = t & 63, w = t >> 6, l15 = lane & 15, kg = lane >> 4;
  if (t < 11) {
    ae2[t] = make_float2(pla.a[t], pla.a[t + 1]);
    mcs[t] = make_float2(pla.m[t], pla.c[t]);
  }
  float pref = (qscale(scal, S_YQ) * qscale(scal, S_YK)) * 0.125f;
  float dmLocal = 3.4e38f;
  i32x4 zero = {0, 0, 0, 0};
  int unit0 = blockIdx.x * 4;
  int bh = unit0 >> 5;                 // all 4 units share bh (unit0 % 4 == 0, 32 units/bh)
  const int8_t* qbase = qq + (size_t)bh * 32768;
  const int8_t* kbase = qk + (size_t)bh * 32768;
#pragma unroll
  for (int k = 0; k < 4; ++k) {
    int unit = unit0 + k, rb = unit & 31;
    i32x4 qf = *(const i32x4*)(qbase + (size_t)(rb * 16 + l15) * 64 + kg * 16);
    i32x4 acc[8];
#pragma unroll
    for (int i = 0; i < 8; ++i) {
      i32x4 kf = *(const i32x4*)(kbase + (size_t)((w * 8 + i) * 16 + l15) * 64 + kg * 16);
      acc[i] = __builtin_amdgcn_mfma_i32_16x16x64_i8(kf, qf, zero, 0, 0, 0);
    }
    float v[8][4];
    float mx = -3.4e38f;
#pragma unroll
    for (int i = 0; i < 8; ++i)
#pragma unroll
      for (int r = 0; r < 4; ++r) {
        v[i][r] = (float)acc[i][r] * pref;
        mx = fmaxf(mx, v[i][r]);
      }
    mx = fmaxf(mx, __shfl_xor(mx, 16, 64));
    mx = fmaxf(mx, __shfl_xor(mx, 32, 64));
    if (lane < 16) redm[w][l15] = mx;
    __syncthreads();                   // barrier A (covers table init at k=0; reds(u-1) reads done)
    float gm = fmaxf(fmaxf(redm[0][l15], redm[1][l15]), fmaxf(redm[2][l15], redm[3][l15]));
    float s = 0.0f;
#pragma unroll
    for (int i = 0; i < 8; ++i)
#pragma unroll
      for (int r = 0; r < 4; ++r) {
        float x = v[i][r] - gm;
        float sh = rintf(x * 67108864.0f);
        sh = fmaxf(sh, -671088640.0f);
        sh = fminf(sh, 0.0f);
        float xc = sh * (1.0f / 67108864.0f);
        float tf = (xc + 10.0f) * 1.2f;
        int i0 = (int)tf;
        i0 = i0 > 10 ? 10 : i0;
        float2 ee = ae2[i0];
        int idx = i0 + ((i0 < 10 && xc >= ee.y) ? 1 : 0) - ((xc < ee.x) ? 1 : 0);
        float2 mc = mcs[idx];
        float e = mc.x * xc;   // no fma: contract off
        e = e + mc.y;
        v[i][r] = e;
        s += e;
      }
    s += __shfl_xor(s, 16, 64);
    s += __shfl_xor(s, 32, 64);
    if (lane < 16) reds[w][l15] = s;
    __syncthreads();                   // barrier B (redm(u) reads done; reds(u) ready)
    float denom = (((reds[0][l15] + reds[1][l15]) + reds[2][l15]) + reds[3][l15]) + 1e-9f;
    dmLocal = fminf(dmLocal, denom);
    if (q15w) {
      float rdn = refined_rcp(denom);
      int d[16];
#pragma unroll
      for (int i = 0; i < 8; ++i) {
        int q15i[4];
#pragma unroll
        for (int r = 0; r < 4; ++r) {
          float sm32 = fdiv_m(v[i][r] * 32768.0f, denom, rdn);
          q15i[r] = (int)fminf(fmaxf(rintf(sm32), -32768.0f), 32767.0f);
        }
        d[i * 2]     = (q15i[0] & 0xffff) | (q15i[1] << 16);
        d[i * 2 + 1] = (q15i[2] & 0xffff) | (q15i[3] << 16);
      }
      i32x4* q15v = (i32x4*)(q15w + (size_t)unit * 4096);
#pragma unroll
      for (int j = 0; j < 4; ++j) {
        i32x4 pk = { d[4 * j], d[4 * j + 1], d[4 * j + 2], d[4 * j + 3] };
        __builtin_nontemporal_store(pk, &q15v[j * 256 + t]);
      }
    }
  }
  float dm = dmLocal;
  dm = fminf(dm, __shfl_xor(dm, 1, 64));
  dm = fminf(dm, __shfl_xor(dm, 2, 64));
  dm = fminf(dm, __shfl_xor(dm, 4, 64));
  dm = fminf(dm, __shfl_xor(dm, 8, 64));
  dm = fminf(dm, __shfl_xor(dm, 16, 64));
  dm = fminf(dm, __shfl_xor(dm, 32, 64));
  if (t == 0) atomicMax(scal + S_DMIN, 0x7f800000u - __float_as_uint(dm));
}

__device__ __forceinline__ float derive_sp(const unsigned* scal, const PLA& pla) {
  float dmin = __uint_as_float(0x7f800000u - scal[S_DMIN]);
  float smm = pla.c[10] / dmin;
  float q15m = fminf(fmaxf(rintf(smm * 32768.0f), -32768.0f), 32767.0f);
  return fmaxf((q15m * (1.0f / 32768.0f)) / QMAXF, 1e-8f);
}

__device__ __forceinline__ void attn_pv_tail(const int8_t* __restrict__ vT, int8_t (*Ps)[528],
                                             unsigned* __restrict__ scal, float* __restrict__ ctx,
                                             int rb, int bh, float sp) {
  int t = threadIdx.x, lane = t & 63, w = t >> 6, l15 = lane & 15, kg = lane >> 4;
  int b = bh / 12, h = bh % 12;
  float sv = qscale(scal, S_YV);
  i32x4 pacc = {0, 0, 0, 0};
  const int8_t* vbase = vT + (size_t)bh * 32768 + (size_t)(w * 16 + l15) * 512;
#pragma unroll
  for (int ks = 0; ks < 8; ++ks) {
    i32x4 pf = *(const i32x4*)&Ps[l15][ks * 64 + kg * 16];
    i32x4 vf = *(const i32x4*)(vbase + ks * 64 + kg * 16);
    pacc = __builtin_amdgcn_mfma_i32_16x16x64_i8(pf, vf, pacc, 0, 0, 0);
  }
  float spv = sp * sv;
  float am = 0.0f;
#pragma unroll
  for (int r = 0; r < 4; ++r) {
    int srow = rb * 16 + kg * 4 + r;
    float val = (float)pacc[r] * spv;
    ctx[((size_t)(b * 512 + srow)) * 768 + h * 64 + w * 16 + l15] = val;
    am = fmaxf(am, fabsf(val));
  }
  block_atomic_maxf(am, scal + S_CTX);
}

// ---------------- pass2_load: 4 units/block, ping-pong q15 prefetch, shared V-tile ----------------
// unit0 = 4*blk: all 4 units share bh -> V-tile loaded once (L1/L2-warm after unit 0).
// Depth-1 software pipeline: prefetch unit u+1's q15 (nontemporal dwordx4) before requant of
// unit u; fully unrolled so pkA/pkB indexing is static (no scratch). Math identical to R14.

__global__ __launch_bounds__(256) void attn_pass2_load(const int* __restrict__ q15r,
                                                       const int8_t* __restrict__ vT,
                                                       unsigned* __restrict__ scal,
                                                       float* __restrict__ ctx, PLA pla) {
  __shared__ alignas(16) int8_t Ps[16][528];
  int t = threadIdx.x, lane = t & 63, w = t >> 6, l15 = lane & 15, kg = lane >> 4;
  int unit0 = blockIdx.x * 4;
  int bh = unit0 >> 5;
  int b = bh / 12, h = bh % 12;
  float sp = derive_sp(scal, pla);
  float rsp = refined_rcp(sp);
  float sv = qscale(scal, S_YV);
  float spv = sp * sv;
  const i32x4* qbase = (const i32x4*)(q15r + (size_t)unit0 * 4096);
  i32x4 pkA[4], pkB[4];
#pragma unroll
  for (int j = 0; j < 4; ++j) pkA[j] = __builtin_nontemporal_load(&qbase[j * 256 + t]);
  const int8_t* vbase = vT + (size_t)bh * 32768 + (size_t)(w * 16 + l15) * 512;
  float am = 0.0f;
#pragma unroll
  for (int u = 0; u < 4; ++u) {
    if (u < 3) {                       // prefetch next unit into the other buffer
      const i32x4* np = qbase + (size_t)(u + 1) * 1024;
      if ((u & 1) == 0) {
#pragma unroll
        for (int j = 0; j < 4; ++j) pkB[j] = __builtin_nontemporal_load(&np[j * 256 + t]);
      } else {
#pragma unroll
        for (int j = 0; j < 4; ++j) pkA[j] = __builtin_nontemporal_load(&np[j * 256 + t]);
      }
    }
    int rb = (unit0 + u) & 31;
#pragma unroll
    for (int i = 0; i < 8; ++i) {
      int jj = i >> 1, e0 = (i & 1) * 2;
      int u01 = ((u & 1) == 0) ? pkA[jj][e0]     : pkB[jj][e0];
      int u23 = ((u & 1) == 0) ? pkA[jj][e0 + 1] : pkB[jj][e0 + 1];
      int q15i[4] = { (int)(short)(u01 & 0xffff), u01 >> 16,
                      (int)(short)(u23 & 0xffff), u23 >> 16 };
      uint32_t packed = 0;
#pragma unroll
      for (int r = 0; r < 4; ++r) {
        float pv = (float)q15i[r] * (1.0f / 32768.0f);
        int qp = (int)fminf(fmaxf(rintf(fdiv_m(pv, sp, rsp)), -QMAXF), QMAXF);
        packed |= (uint32_t)(qp & 255) << (8 * r);
      }
      *(uint32_t*)&Ps[l15][(w * 8 + i) * 16 + kg * 4] = packed;
    }
    __syncthreads();                   // Ps(u) complete
    i32x4 pacc = {0, 0, 0, 0};
#pragma unroll
    for (int ks = 0; ks < 8; ++ks) {
      i32x4 pf = *(const i32x4*)&Ps[l15][ks * 64 + kg * 16];
      i32x4 vf = *(const i32x4*)(vbase + ks * 64 + kg * 16);
      pacc = __builtin_amdgcn_mfma_i32_16x16x64_i8(pf, vf, pacc, 0, 0, 0);
    }
#pragma unroll
    for (int r = 0; r < 4; ++r) {
      int srow = rb * 16 + kg * 4 + r;
      float val = (float)pacc[r] * spv;
      ctx[((size_t)(b * 512 + srow)) * 768 + h * 64 + w * 16 + l15] = val;
      am = fmaxf(am, fabsf(val));
    }
    __syncthreads();                   // PV(u) reads done before Ps(u+1) writes
  }
  block_atomic_maxf(am, scal + S_CTX);
}

// fallback pass2: recompute e-phase, quantize, PV (R6 path)
__global__ __launch_bounds__(256) void attn_pass2_recompute(const int8_t* __restrict__ qq,
                                                            const int8_t* __restrict__ qk,
                                                            const int8_t* __restrict__ vT,
                                                            unsigned* __restrict__ scal,
                                                            float* __restrict__ ctx, PLA pla) {
  __shared__ float red[4][16];
  __shared__ alignas(16) int8_t Ps[16][528];
  int rb = blockIdx.x & 31, bh = blockIdx.x >> 5;
  float pref = (qscale(scal, S_YQ) * qscale(scal, S_YK)) * 0.125f;
  float sp = derive_sp(scal, pla);
  float rsp = refined_rcp(sp);
  float v[8][4];
  float denom;
  attn_e_phase(qq + (size_t)bh * 32768, qk + (size_t)bh * 32768, rb, pref, pla, v, red, denom);
  float rdn = refined_rcp(denom);
  int t = threadIdx.x, lane = t & 63, w = t >> 6, l15 = lane & 15, kg = lane >> 4;
#pragma unroll
  for (int i = 0; i < 8; ++i) {
    uint32_t packed = 0;
#pragma unroll
    for (int r = 0; r < 4; ++r) {
      float sm32 = fdiv_m(v[i][r] * 32768.0f, denom, rdn);
      float q15 = fminf(fmaxf(rintf(sm32), -32768.0f), 32767.0f);
      float pv = q15 * (1.0f / 32768.0f);
      int qp = (int)fminf(fmaxf(rintf(fdiv_m(pv, sp, rsp)), -QMAXF), QMAXF);
      packed |= (uint32_t)(qp & 255) << (8 * r);
    }
    *(uint32_t*)&Ps[l15][(w * 8 + i) * 16 + kg * 4] = packed;
  }
  __syncthreads();
  attn_pv_tail(vT, Ps, scal, ctx, rb, bh, sp);
}

// ---------------- collapsed ctx double-quant + qbias_o (R9-proven) ----------------
// q2 == q0 identity (R8-proven): with ctxq1max = fl(127*s1), s2 = s1*(1 +- 1ulp), so
// rint(q0*s1/s2) == q0 for |q0|<=127. qctx2 = q0 directly; S_CTXQ1 <- fl(127*s1).

__global__ __launch_bounds__(256) void ctx_q12_plus(const float4* __restrict__ ctx, int* __restrict__ q2o,
                                                    const float* __restrict__ bo, float* __restrict__ qbo,
                                                    unsigned* __restrict__ scal) {
  int blk = blockIdx.x;
  float s1 = qscale(scal, S_CTX);
  float ctxq1max = 127.0f * s1;
  if (blk < 3072) {
    float rs1 = refined_rcp(s1);
    int i = blk * 256 + threadIdx.x;
    float4 c = ctx[i];
    int q0 = (int)fminf(fmaxf(rintf(fdiv_m(c.x, s1, rs1)), -QMAXF), QMAXF);
    int q1 = (int)fminf(fmaxf(rintf(fdiv_m(c.y, s1, rs1)), -QMAXF), QMAXF);
    int q2 = (int)fminf(fmaxf(rintf(fdiv_m(c.z, s1, rs1)), -QMAXF), QMAXF);
    int q3 = (int)fminf(fmaxf(rintf(fdiv_m(c.w, s1, rs1)), -QMAXF), QMAXF);
    q2o[i] = (q0 & 255) | ((q1 & 255) << 8) | ((q2 & 255) << 16) | ((q3 & 255) << 24);
  } else {
    if (blk == 3072 && threadIdx.x == 0) scal[S_CTXQ1] = __float_as_uint(ctxq1max);
    int j = (blk - 3072) * 256 + threadIdx.x;
    if (j < 768) {
      float in_scale = ctxq1max / QMAXF;   // no clamp (reference)
      float w_scale = __uint_as_float(scal[S_WO]) / QMAXF;
      float bias_scale = in_scale * w_scale;
      float tmax = __uint_as_float(scal[S_BO]) / bias_scale;
      float st = fmaxf(tmax / QMAXF, 1e-8f);
      float tv = bo[j] / bias_scale;
      float qv = fminf(fmaxf(rintf(tv / st), -127.0f), 127.0f) * st;
      qbo[j] = qv * bias_scale;
    }
  }
}

// ---------------- host: PLA build (replicates np.polyfit degree-1 LS in f64) ----------------

static void build_pla(PLA& p) {
  double xs[1001], ys[1001];
  double step = 10.0 / 1000.0;
  for (int j = 0; j <= 1000; ++j) xs[j] = (double)j * step + (-10.0);
  xs[1000] = 0.0;
  for (int j = 0; j <= 1000; ++j) ys[j] = exp(xs[j]);
  double estep = 10.0 / 12.0;
  for (int i = 0; i < 12; ++i) {
    double a = (double)i * estep + (-10.0);
    double bb = (i + 1 == 12) ? 0.0 : (double)(i + 1) * estep + (-10.0);
    double n = 0, Sx = 0, Sy = 0, Sxx = 0, Sxy = 0;
    for (int j = 0; j <= 1000; ++j) {
      if (xs[j] >= a && xs[j] <= bb) {
        double x = xs[j], y = ys[j];
        n += 1.0; Sx += x; Sy += y; Sxx += x * x; Sxy += x * y;
      }
    }
    double det = n * Sxx - Sx * Sx;
    p.m[i] = (float)((n * Sxy - Sx * Sy) / det);
    p.c[i] = (float)((Sxx * Sy - Sx * Sxy) / det);
    p.a[i] = (float)a;
  }
}

// ---------------- launch ----------------

extern "C" void kernel_launch(void* const* d_in, const int* in_sizes, int n_in,
                              void* d_out, int out_size, void* d_ws, size_t ws_size,
                              hipStream_t stream) {
  const float* X  = (const float*)d_in[0];
  const float* Wq = (const float*)d_in[1];
  const float* bq = (const float*)d_in[2];
  const float* Wk = (const float*)d_in[3];
  const float* bk = (const float*)d_in[4];
  const float* Wv = (const float*)d_in[5];
  const float* bv = (const float*)d_in[6];
  const float* Wo = (const float*)d_in[7];
  const float* bo = (const float*)d_in[8];
  float* out = (float*)d_out;
  (void)n_in; (void)in_sizes; (void)out_size;

  PLA pla;
  build_pla(pla);

  const size_t NX = 8 * 512 * 768;   // 3145728
  const size_t NW = 768 * 768;       // 589824
  const size_t Q15_BYTES = 3072ull * 16384;  // 48 MiB

  uint8_t* ws = (uint8_t*)d_ws;
  size_t off = 0;
  auto alloc = [&](size_t bytes) -> void* {
    void* p = ws + off;
    off += (bytes + 255) & ~(size_t)255;
    return p;
  };

  unsigned* scal = (unsigned*)alloc(256);
  int8_t* qWq = (int8_t*)alloc(NW);
  int8_t* qWk = (int8_t*)alloc(NW);
  int8_t* qWv = (int8_t*)alloc(NW);
  int8_t* qWo = (int8_t*)alloc(NW);
  float* qbq = (float*)alloc(768 * 4);
  float* qbk = (float*)alloc(768 * 4);
  float* qbv = (float*)alloc(768 * 4);
  float* qbo = (float*)alloc(768 * 4);
  int8_t* qX = (int8_t*)alloc(NX);       // reused as qctx2
  int8_t* qctx2 = qX;

  size_t fixed = off;
  size_t need_fast = fixed + Q15_BYTES + (4 * NX) + NX + 512;
  bool fast = ws_size >= need_fast;

  zero_scal<<<1, 64, 0, stream>>>(scal);   // replaces hipMemsetAsync (fillBuffer was 42us in-graph)

  if (fast) {
    uint8_t* D = (uint8_t*)alloc(Q15_BYTES);        // Yq|Yk|Yv then q15
    float* Yq = (float*)D;
    float* Yk = (float*)(D + NX * 4);
    float* Yv = (float*)(D + 2 * NX * 4);
    int* q15buf = (int*)D;
    uint8_t* E = (uint8_t*)alloc(4 * NX);           // qq|qk then ctx
    int8_t* qq = (int8_t*)E;
    int8_t* qk = (int8_t*)(E + NX);
    float* ctx = (float*)E;
    int8_t* qvT = (int8_t*)alloc(NX);

    maxabs_all<<<1604, 256, 0, stream>>>((const float4*)X, (const float4*)Wq, (const float4*)Wk,
                                         (const float4*)Wv, (const float4*)Wo, bq, bk, bv, bo, scal);
    quant_all<<<1609, 256, 0, stream>>>((const float4*)X, (int*)qX,
                                        (const float4*)Wq, (const float4*)Wk, (const float4*)Wv, (const float4*)Wo,
                                        (int*)qWq, (int*)qWk, (int*)qWv, (int*)qWo,
                                        bq, bk, bv, qbq, qbk, qbv, scal);
    gemm_qkv<<<dim3(12, 32, 3), 256, 0, stream>>>(qX, qWq, qWk, qWv, qbq, qbk, qbv, Yq, Yk, Yv, scal);
    quant_heads_all<<<6912, 256, 0, stream>>>(Yq, (int*)qq, Yk, (int*)qk, Yv, qvT, scal);
    attn_pass1<<<768, 256, 0, stream>>>(qq, qk, q15buf, scal, pla);          // q15 overwrites Y (dead)
    attn_pass2_load<<<768, 256, 0, stream>>>(q15buf, qvT, scal, ctx, pla);   // ctx overwrites qq/qk (dead)
    ctx_q12_plus<<<3075, 256, 0, stream>>>((const float4*)ctx, (int*)qctx2, bo, qbo, scal);
    gemm_proj<<<dim3(12, 32), 256, 0, stream>>>(qctx2, qWo, out, qbo, scal, S_CTXQ1, S_WO, -1);
  } else {
    float* Y = (float*)alloc(NX * 4);               // then ctx
    float* ctx = Y;
    int8_t* qq = (int8_t*)alloc(NX);
    int8_t* qk = (int8_t*)alloc(NX);
    int8_t* qvT = (int8_t*)alloc(NX);

    maxabs_all<<<1604, 256, 0, stream>>>((const float4*)X, (const float4*)Wq, (const float4*)Wk,
                                         (const float4*)Wv, (const float4*)Wo, bq, bk, bv, bo, scal);
    quant_all<<<1609, 256, 0, stream>>>((const float4*)X, (int*)qX,
                                        (const float4*)Wq, (const float4*)Wk, (const float4*)Wv, (const float4*)Wo,
                                        (int*)qWq, (int*)qWk, (int*)qWv, (int*)qWo,
                                        bq, bk, bv, qbq, qbk, qbv, scal);
    gemm_proj<<<dim3(12, 32), 256, 0, stream>>>(qX, qWq, Y, qbq, scal, S_X, S_WQ, S_YQ);
    quant_heads_qk<<<3072, 256, 0, stream>>>(Y, (int*)qq, scal, S_YQ);
    gemm_proj<<<dim3(12, 32), 256, 0, stream>>>(qX, qWk, Y, qbk, scal, S_X, S_WK, S_YK);
    quant_heads_qk<<<3072, 256, 0, stream>>>(Y, (int*)qk, scal, S_YK);
    gemm_proj<<<dim3(12, 32), 256, 0, stream>>>(qX, qWv, Y, qbv, scal, S_X, S_WV, S_YV);
    quant_heads_v<<<768, 256, 0, stream>>>(Y, qvT, scal);
    attn_pass1<<<768, 256, 0, stream>>>(qq, qk, (int*)nullptr, scal, pla);
    attn_pass2_recompute<<<3072, 256, 0, stream>>>(qq, qk, qvT, scal, ctx, pla);
    ctx_q12_plus<<<3075, 256, 0, stream>>>((const float4*)ctx, (int*)qctx2, bo, qbo, scal);
    gemm_proj<<<dim3(12, 32), 256, 0, stream>>>(qctx2, qWo, out, qbo, scal, S_CTXQ1, S_WO, -1);
  }
}